// Round 1
// baseline (4753.310 us; speedup 1.0000x reference)
//
#include <hip/hip_runtime.h>
#include <cmath>

#define NP    513
#define NPP   516          // padded row stride for DtD / D (16B-aligned float4 rows)
#define T_LEN 64
#define JNT   512
#define BATCH 32
#define NITER 30
#define LAMBDA_F 0.1f

// workspace layout (float offsets)
#define O_DRAWT 0                       // D_raw transposed [NP][64]
#define O_D     32832                   // D row-major [64][NPP]
#define O_DTD   65856                   // DtD [NP][NPP] (pad cols zeroed)
#define O_L     330564                  // [0]=L, [1]=thresh
#define O_DTY   330624                  // [B][NP][J]
#define O_CA    8735616                 // C_prev ping
#define O_CB    17140608                // C_prev pong
#define C_ELEMS 8404992                 // 32*513*512
#define Y_ELEMS 1048576                 // 32*64*512

__global__ void build_D(const float* __restrict__ r, const float* __restrict__ th,
                        float* __restrict__ ws) {
    int p = blockIdx.x;          // 0..512
    int t = threadIdx.x;         // 0..63 (one wave)
    float val;
    if (p == 0) {
        val = 1.0f;
    } else if (p <= 256) {
        int n = p - 1;
        val = powf(r[n], (float)t) * cosf((float)t * th[n]);
    } else {
        int n = p - 257;
        val = powf(r[n], (float)t) * sinf((float)t * th[n]);
    }
    float s = val * val;
    #pragma unroll
    for (int off = 32; off; off >>= 1) s += __shfl_xor(s, off);
    float norm = sqrtf(s);
    ws[O_DRAWT + p * 64 + t] = val;           // transposed raw dict
    ws[O_D + t * NPP + p]    = val / norm;    // normalized dict, row-major padded
}

__global__ void dtd_kernel(float* __restrict__ ws) {
    int idx = blockIdx.x * 256 + threadIdx.x;
    if (idx >= NP * NP) return;
    int p = idx / NP, q = idx % NP;
    const float* D = ws + O_D;
    float s = 0.0f;
    #pragma unroll 8
    for (int t = 0; t < T_LEN; t++) s = fmaf(D[t * NPP + p], D[t * NPP + q], s);
    ws[O_DTD + (size_t)p * NPP + q] = s;
}

__global__ void lnorm_kernel(float* __restrict__ ws) {
    __shared__ double sd[256];
    int tid = threadIdx.x;
    double acc = 0.0;
    const float* dtd = ws + O_DTD;
    for (int i = tid; i < NP * NPP; i += 256) { double v = dtd[i]; acc += v * v; }
    sd[tid] = acc; __syncthreads();
    for (int off = 128; off; off >>= 1) {
        if (tid < off) sd[tid] += sd[tid + off];
        __syncthreads();
    }
    if (tid == 0) {
        float L = (float)(1.0 / sqrt(sd[0]));
        ws[O_L] = L;
        ws[O_L + 1] = L * LAMBDA_F;
    }
}

// DtY[b,p,j] = sum_t D[t,p] * y[b,t,j].  64x64 output tile, K=64.
__global__ __launch_bounds__(256) void dty_kernel(const float* __restrict__ y,
                                                  float* __restrict__ ws) {
    __shared__ float As[T_LEN][64];   // [t][p]
    __shared__ float Bs[T_LEN][64];   // [t][j]
    int tid = threadIdx.x;
    int p0 = blockIdx.x * 64, j0 = blockIdx.y * 64, b = blockIdx.z;
    const float* D = ws + O_D;
    #pragma unroll
    for (int i = 0; i < 4; i++) {
        int lin = i * 256 + tid;                // 0..1023 float4s
        int kt = lin >> 4, pg = lin & 15;
        float4 v = make_float4(0, 0, 0, 0);
        int pp = p0 + pg * 4;
        if (pp < NPP) v = *(const float4*)&D[kt * NPP + pp];   // pad cols are zero
        *(float4*)&As[kt][pg * 4] = v;
    }
    #pragma unroll
    for (int i = 0; i < 4; i++) {
        int lin = i * 256 + tid;
        int kt = lin >> 4, jg = lin & 15;
        *(float4*)&Bs[kt][jg * 4] =
            *(const float4*)&y[((size_t)b * T_LEN + kt) * JNT + j0 + jg * 4];
    }
    __syncthreads();
    int ty = tid >> 4, tx = tid & 15;
    float acc[4][4] = {};
    #pragma unroll 8
    for (int k = 0; k < T_LEN; k++) {
        float4 a  = *(float4*)&As[k][ty * 4];
        float4 bv = *(float4*)&Bs[k][tx * 4];
        float av[4] = {a.x, a.y, a.z, a.w};
        float bw[4] = {bv.x, bv.y, bv.z, bv.w};
        #pragma unroll
        for (int i2 = 0; i2 < 4; i2++)
            #pragma unroll
            for (int jj = 0; jj < 4; jj++)
                acc[i2][jj] = fmaf(av[i2], bw[jj], acc[i2][jj]);
    }
    float* DtY = ws + O_DTY;
    #pragma unroll
    for (int i2 = 0; i2 < 4; i2++) {
        int p = p0 + ty * 4 + i2;
        if (p >= NP) continue;
        size_t base = ((size_t)b * NP + p) * JNT + j0 + tx * 4;
        *(float4*)&DtY[base] = make_float4(acc[i2][0], acc[i2][1], acc[i2][2], acc[i2][3]);
    }
}

// One FISTA step: grad = DtD@C_prev - DtY; C_next = ST(C_prev - L*grad, L*lam);
// C_prev_out = C_next + tc*(C_next - C_curr); C_curr = C_next.
__global__ __launch_bounds__(256) void fista_kernel(const float* __restrict__ ws_c,
                                                    const float* __restrict__ Cin,
                                                    float* __restrict__ Cout,
                                                    float* __restrict__ Ccur,
                                                    float tconst) {
    __shared__ float As[32][64];  // [kq][p]  (DtD symmetric: row q, cols p -> aligned f4)
    __shared__ float Bs[32][64];  // [kq][j]
    int tid = threadIdx.x;
    int p0 = blockIdx.x * 64, j0 = blockIdx.y * 64, b = blockIdx.z;
    const float* DtD = ws_c + O_DTD;
    const float* DtY = ws_c + O_DTY;
    float acc[4][4] = {};
    int ty = tid >> 4, tx = tid & 15;
    for (int kc = 0; kc < 17; kc++) {
        int q0 = kc * 32;
        #pragma unroll
        for (int i = 0; i < 2; i++) {
            int lin = i * 256 + tid;            // 0..511 float4s
            int kq = lin >> 4, pg = lin & 15;
            float4 v = make_float4(0, 0, 0, 0);
            int q = q0 + kq, pp = p0 + pg * 4;
            if (q < NP && pp < NPP) v = *(const float4*)&DtD[(size_t)q * NPP + pp];
            *(float4*)&As[kq][pg * 4] = v;
        }
        #pragma unroll
        for (int i = 0; i < 2; i++) {
            int lin = i * 256 + tid;
            int kq = lin >> 4, jg = lin & 15;
            float4 v = make_float4(0, 0, 0, 0);
            int q = q0 + kq;
            if (q < NP) v = *(const float4*)&Cin[((size_t)b * NP + q) * JNT + j0 + jg * 4];
            *(float4*)&Bs[kq][jg * 4] = v;
        }
        __syncthreads();
        #pragma unroll
        for (int k = 0; k < 32; k++) {
            float4 a  = *(float4*)&As[k][ty * 4];
            float4 bv = *(float4*)&Bs[k][tx * 4];
            float av[4] = {a.x, a.y, a.z, a.w};
            float bw[4] = {bv.x, bv.y, bv.z, bv.w};
            #pragma unroll
            for (int i2 = 0; i2 < 4; i2++)
                #pragma unroll
                for (int jj = 0; jj < 4; jj++)
                    acc[i2][jj] = fmaf(av[i2], bw[jj], acc[i2][jj]);
        }
        __syncthreads();
    }
    float L   = ws_c[O_L];
    float thr = ws_c[O_L + 1];
    #pragma unroll
    for (int i2 = 0; i2 < 4; i2++) {
        int p = p0 + ty * 4 + i2;
        if (p >= NP) continue;
        size_t base = ((size_t)b * NP + p) * JNT + j0 + tx * 4;
        float4 dty = *(const float4*)&DtY[base];
        float4 cp  = *(const float4*)&Cin[base];
        float4 cc  = *(const float4*)&Ccur[base];
        float dv[4] = {dty.x, dty.y, dty.z, dty.w};
        float pv[4] = {cp.x, cp.y, cp.z, cp.w};
        float cv[4] = {cc.x, cc.y, cc.z, cc.w};
        float cn[4], po[4];
        #pragma unroll
        for (int jj = 0; jj < 3 + 1; jj++) {
            float g = acc[i2][jj] - dv[jj];
            float v = pv[jj] - L * g;
            float a = fabsf(v) - thr;
            float st = (a > 0.0f) ? copysignf(a, v) : 0.0f;
            cn[jj] = st;
            po[jj] = st + tconst * (st - cv[jj]);
        }
        *(float4*)&Cout[base] = make_float4(po[0], po[1], po[2], po[3]);
        *(float4*)&Ccur[base] = make_float4(cn[0], cn[1], cn[2], cn[3]);
    }
}

// Y[b,t,j] = sum_p D_raw[t,p] * C[b,p,j].  64(t) x 64(j) tile, K=513.
__global__ __launch_bounds__(256) void ypred_kernel(const float* __restrict__ ws_c,
                                                    const float* __restrict__ C,
                                                    float* __restrict__ Y) {
    __shared__ float As[32][64];  // [kp][t]
    __shared__ float Bs[32][64];  // [kp][j]
    int tid = threadIdx.x;
    int j0 = blockIdx.x * 64, b = blockIdx.y;
    const float* DrawT = ws_c + O_DRAWT;
    float acc[4][4] = {};
    int ty = tid >> 4, tx = tid & 15;
    for (int kc = 0; kc < 17; kc++) {
        int p0 = kc * 32;
        #pragma unroll
        for (int i = 0; i < 2; i++) {
            int lin = i * 256 + tid;
            int kp = lin >> 4, tg = lin & 15;
            float4 v = make_float4(0, 0, 0, 0);
            int p = p0 + kp;
            if (p < NP) v = *(const float4*)&DrawT[(size_t)p * 64 + tg * 4];
            *(float4*)&As[kp][tg * 4] = v;
        }
        #pragma unroll
        for (int i = 0; i < 2; i++) {
            int lin = i * 256 + tid;
            int kp = lin >> 4, jg = lin & 15;
            float4 v = make_float4(0, 0, 0, 0);
            int p = p0 + kp;
            if (p < NP) v = *(const float4*)&C[((size_t)b * NP + p) * JNT + j0 + jg * 4];
            *(float4*)&Bs[kp][jg * 4] = v;
        }
        __syncthreads();
        #pragma unroll
        for (int k = 0; k < 32; k++) {
            float4 a  = *(float4*)&As[k][ty * 4];
            float4 bv = *(float4*)&Bs[k][tx * 4];
            float av[4] = {a.x, a.y, a.z, a.w};
            float bw[4] = {bv.x, bv.y, bv.z, bv.w};
            #pragma unroll
            for (int i2 = 0; i2 < 4; i2++)
                #pragma unroll
                for (int jj = 0; jj < 4; jj++)
                    acc[i2][jj] = fmaf(av[i2], bw[jj], acc[i2][jj]);
        }
        __syncthreads();
    }
    #pragma unroll
    for (int i2 = 0; i2 < 4; i2++) {
        int t = ty * 4 + i2;
        size_t base = ((size_t)b * T_LEN + t) * JNT + j0 + tx * 4;
        *(float4*)&Y[base] = make_float4(acc[i2][0], acc[i2][1], acc[i2][2], acc[i2][3]);
    }
}

extern "C" void kernel_launch(void* const* d_in, const int* in_sizes, int n_in,
                              void* d_out, int out_size, void* d_ws, size_t ws_size,
                              hipStream_t stream) {
    const float* y  = (const float*)d_in[0];
    const float* r  = (const float*)d_in[1];
    const float* th = (const float*)d_in[2];
    float* ws  = (float*)d_ws;
    float* out = (float*)d_out;
    float* Ccur = out + Y_ELEMS;   // C_pred region of d_out doubles as C_curr

    // zero: D pads, DtD pads, C_prev ping, C_curr
    hipMemsetAsync(ws + O_D,   0, (size_t)(T_LEN * NPP) * 4, stream);
    hipMemsetAsync(ws + O_DTD, 0, (size_t)(NP * NPP) * 4, stream);
    hipMemsetAsync(ws + O_CA,  0, (size_t)C_ELEMS * 4, stream);
    hipMemsetAsync(Ccur,       0, (size_t)C_ELEMS * 4, stream);

    build_D<<<NP, 64, 0, stream>>>(r, th, ws);
    dtd_kernel<<<(NP * NP + 255) / 256, 256, 0, stream>>>(ws);
    lnorm_kernel<<<1, 256, 0, stream>>>(ws);
    dty_kernel<<<dim3(9, 8, 32), 256, 0, stream>>>(y, ws);

    float* CA = ws + O_CA;
    float* CB = ws + O_CB;
    float t_prev = 1.0f;
    for (int it = 0; it < NITER; ++it) {
        float t_next = (1.0f + sqrtf(1.0f + 4.0f * t_prev * t_prev)) * 0.5f;
        float tconst = (t_prev - 1.0f) / t_next;
        const float* Cin = (it & 1) ? CB : CA;
        float*       Cot = (it & 1) ? CA : CB;
        fista_kernel<<<dim3(9, 8, 32), 256, 0, stream>>>(ws, Cin, Cot, Ccur, tconst);
        t_prev = t_next;
    }

    ypred_kernel<<<dim3(8, 32), 256, 0, stream>>>(ws, Ccur, out);
}

// Round 2
// 3440.570 us; speedup vs baseline: 1.3815x; 1.3815x over previous
//
#include <hip/hip_runtime.h>
#include <cmath>

#define NP    513
#define NPP   516          // padded stride for D rows / Cprev p-dim
#define T_LEN 64
#define JNT   512
#define BATCH 32
#define NITER 30

// d_out layout (floats): [0..348160) DtD fp32 [640][544]; [348160..348226) lnorm
// partials+L+thr; overwritten by ypred at the end. [1048576..) C_pred = C_curr.
#define DTD_ROWS 640
#define DTD_STR  544
#define DTD_F    (DTD_ROWS * DTD_STR)      // 348160
#define LN_OFF   DTD_F
#define Y_ELEMS  1048576                   // 32*64*512
#define C_ELEMS  8404992                   // 32*513*512

// ws layout (floats)
#define O_DRAWT 0                          // [513][64] f32
#define O_D     32832                      // [64][516] f32 (pad cols zeroed)
#define O_DTY   65856                      // [32][513][512] f32
#define O_CA    8470848                    // [32][512][516] f32  C_prev ping ([b][j][p])
#define O_CB    16924992                   // C_prev pong
#define CP_ELEMS 8454144                   // 32*512*516

typedef short   short8   __attribute__((ext_vector_type(8)));
typedef float   f32x4    __attribute__((ext_vector_type(4)));

__device__ __forceinline__ unsigned short f2bf(float f) {
    unsigned u = __float_as_uint(f);
    return (unsigned short)((u + 0x7fffu + ((u >> 16) & 1u)) >> 16);
}
__device__ __forceinline__ void split2(float f, unsigned short& h, unsigned short& l) {
    unsigned short hs = f2bf(f);
    float hf = __uint_as_float((unsigned)hs << 16);
    h = hs;
    l = f2bf(f - hf);
}

__global__ void build_D(const float* __restrict__ r, const float* __restrict__ th,
                        float* __restrict__ ws) {
    int p = blockIdx.x;          // 0..512
    int t = threadIdx.x;         // 0..63
    float val;
    if (p == 0) {
        val = 1.0f;
    } else if (p <= 256) {
        int n = p - 1;
        val = powf(r[n], (float)t) * cosf((float)t * th[n]);
    } else {
        int n = p - 257;
        val = powf(r[n], (float)t) * sinf((float)t * th[n]);
    }
    float s = val * val;
    #pragma unroll
    for (int off = 32; off; off >>= 1) s += __shfl_xor(s, off);
    float norm = sqrtf(s);
    ws[O_DRAWT + p * 64 + t] = val;
    ws[O_D + t * NPP + p]    = val / norm;
}

__global__ void dtd_kernel(const float* __restrict__ ws, float* __restrict__ dtd_out) {
    int idx = blockIdx.x * 256 + threadIdx.x;
    if (idx >= NP * NP) return;
    int p = idx / NP, q = idx % NP;
    const float* D = ws + O_D;
    float s = 0.0f;
    #pragma unroll 8
    for (int t = 0; t < T_LEN; t++) s = fmaf(D[t * NPP + p], D[t * NPP + q], s);
    dtd_out[(size_t)p * DTD_STR + q] = s;
}

// stage 1: 64 blocks, each sums squares of a 5440-float chunk of DtD (incl. zero pads)
__global__ __launch_bounds__(256) void lnorm1(const float* __restrict__ dtd_s,
                                              float* __restrict__ ln) {
    __shared__ float sm[256];
    int tid = threadIdx.x;
    size_t base = (size_t)blockIdx.x * 5440;
    float acc = 0.0f;
    for (int i = tid; i < 1360; i += 256) {
        float4 v = *(const float4*)&dtd_s[base + (size_t)i * 4];
        acc += v.x * v.x + v.y * v.y + v.z * v.z + v.w * v.w;
    }
    sm[tid] = acc; __syncthreads();
    for (int off = 128; off; off >>= 1) {
        if (tid < off) sm[tid] += sm[tid + off];
        __syncthreads();
    }
    if (tid == 0) ln[blockIdx.x] = sm[0];
}

__global__ void lnorm2(float* __restrict__ ln) {
    int lane = threadIdx.x;      // 64 threads
    float v = ln[lane];
    #pragma unroll
    for (int off = 32; off; off >>= 1) v += __shfl_xor(v, off);
    if (lane == 0) {
        float L = 1.0f / sqrtf(v);
        ln[64] = L;
        ln[65] = L * 0.1f;
    }
}

// DtY[b,p,j] = sum_t D[t,p] * y[b,t,j].  64x64 tile, K=64.
__global__ __launch_bounds__(256) void dty_kernel(const float* __restrict__ y,
                                                  float* __restrict__ ws) {
    __shared__ float As[T_LEN][64];
    __shared__ float Bs[T_LEN][64];
    int tid = threadIdx.x;
    int p0 = blockIdx.x * 64, j0 = blockIdx.y * 64, b = blockIdx.z;
    const float* D = ws + O_D;
    #pragma unroll
    for (int i = 0; i < 4; i++) {
        int lin = i * 256 + tid;
        int kt = lin >> 4, pg = lin & 15;
        float4 v = make_float4(0, 0, 0, 0);
        int pp = p0 + pg * 4;
        if (pp < NPP) v = *(const float4*)&D[kt * NPP + pp];
        *(float4*)&As[kt][pg * 4] = v;
    }
    #pragma unroll
    for (int i = 0; i < 4; i++) {
        int lin = i * 256 + tid;
        int kt = lin >> 4, jg = lin & 15;
        *(float4*)&Bs[kt][jg * 4] =
            *(const float4*)&y[((size_t)b * T_LEN + kt) * JNT + j0 + jg * 4];
    }
    __syncthreads();
    int ty = tid >> 4, tx = tid & 15;
    float acc[4][4] = {};
    #pragma unroll 8
    for (int k = 0; k < T_LEN; k++) {
        float4 a  = *(float4*)&As[k][ty * 4];
        float4 bv = *(float4*)&Bs[k][tx * 4];
        float av[4] = {a.x, a.y, a.z, a.w};
        float bw[4] = {bv.x, bv.y, bv.z, bv.w};
        #pragma unroll
        for (int i2 = 0; i2 < 4; i2++)
            #pragma unroll
            for (int jj = 0; jj < 4; jj++)
                acc[i2][jj] = fmaf(av[i2], bw[jj], acc[i2][jj]);
    }
    float* DtY = ws + O_DTY;
    #pragma unroll
    for (int i2 = 0; i2 < 4; i2++) {
        int p = p0 + ty * 4 + i2;
        if (p >= NP) continue;
        size_t base = ((size_t)b * NP + p) * JNT + j0 + tx * 4;
        *(float4*)&DtY[base] = make_float4(acc[i2][0], acc[i2][1], acc[i2][2], acc[i2][3]);
    }
}

// FISTA step with bf16 split-precision MFMA.
// DtD@Cprev via (Ah+Al)@(Bh+Bl) ~= AhBh + AlBh + AhBl.
// Tile: BM=128(p) x BN=64(j), BK=32. 4 waves, each 64x32 (4x2 frags 16x16x32).
#define BM 128
#define BN 64
#define BK 32
#define LDK 40
__global__ __launch_bounds__(256) void fista_mfma(
    const float* __restrict__ dtd_s,    // [640][544]
    const float* __restrict__ lnv,      // L at [64], thr at [65]
    const float* __restrict__ dty,      // [32][513][512]
    const float* __restrict__ Cin,      // [32][512][516]
    float* __restrict__ Cout,           // [32][512][516]
    float* __restrict__ Ccur,           // [32][513][512] (d_out C region)
    float tconst)
{
    __shared__ unsigned short Ah[BM * LDK], Al[BM * LDK];
    __shared__ unsigned short Bh[BN * LDK], Bl[BN * LDK];
    int tid = threadIdx.x;
    int p0 = blockIdx.x * BM, j0 = blockIdx.y * BN, b = blockIdx.z;
    int lane = tid & 63, wid = tid >> 6;
    int wrow = wid >> 1, wcol = wid & 1;
    int l15 = lane & 15, l4 = lane >> 4;

    f32x4 acc[4][2] = {};

    for (int kc = 0; kc < 17; ++kc) {
        int q0 = kc * BK;
        // stage A: 128x32 fp32 -> split hi/lo bf16
        #pragma unroll
        for (int i = 0; i < 4; ++i) {
            int c = i * 256 + tid;
            int prow = c >> 3, qg = c & 7;
            float4 v = *(const float4*)&dtd_s[(size_t)(p0 + prow) * DTD_STR + q0 + qg * 4];
            unsigned short hs[4], ls[4];
            split2(v.x, hs[0], ls[0]); split2(v.y, hs[1], ls[1]);
            split2(v.z, hs[2], ls[2]); split2(v.w, hs[3], ls[3]);
            int o = prow * LDK + qg * 4;
            *(ushort4*)&Ah[o] = make_ushort4(hs[0], hs[1], hs[2], hs[3]);
            *(ushort4*)&Al[o] = make_ushort4(ls[0], ls[1], ls[2], ls[3]);
        }
        // stage B: 64x32 fp32 -> split hi/lo bf16 (guard q >= 516)
        #pragma unroll
        for (int i = 0; i < 2; ++i) {
            int c = i * 256 + tid;
            int jrow = c >> 3, qg = c & 7;
            int qoff = q0 + qg * 4;
            float4 v = make_float4(0, 0, 0, 0);
            if (qoff < NPP)
                v = *(const float4*)&Cin[((size_t)b * JNT + j0 + jrow) * NPP + qoff];
            unsigned short hs[4], ls[4];
            split2(v.x, hs[0], ls[0]); split2(v.y, hs[1], ls[1]);
            split2(v.z, hs[2], ls[2]); split2(v.w, hs[3], ls[3]);
            int o = jrow * LDK + qg * 4;
            *(ushort4*)&Bh[o] = make_ushort4(hs[0], hs[1], hs[2], hs[3]);
            *(ushort4*)&Bl[o] = make_ushort4(ls[0], ls[1], ls[2], ls[3]);
        }
        __syncthreads();
        short8 ah[4], al[4], bh[2], bl[2];
        #pragma unroll
        for (int mi = 0; mi < 4; ++mi) {
            int row = wrow * 64 + mi * 16 + l15;
            ah[mi] = *(const short8*)&Ah[row * LDK + l4 * 8];
            al[mi] = *(const short8*)&Al[row * LDK + l4 * 8];
        }
        #pragma unroll
        for (int ni = 0; ni < 2; ++ni) {
            int row = wcol * 32 + ni * 16 + l15;
            bh[ni] = *(const short8*)&Bh[row * LDK + l4 * 8];
            bl[ni] = *(const short8*)&Bl[row * LDK + l4 * 8];
        }
        #pragma unroll
        for (int mi = 0; mi < 4; ++mi)
            #pragma unroll
            for (int ni = 0; ni < 2; ++ni) {
                acc[mi][ni] = __builtin_amdgcn_mfma_f32_16x16x32_bf16(ah[mi], bh[ni], acc[mi][ni], 0, 0, 0);
                acc[mi][ni] = __builtin_amdgcn_mfma_f32_16x16x32_bf16(al[mi], bh[ni], acc[mi][ni], 0, 0, 0);
                acc[mi][ni] = __builtin_amdgcn_mfma_f32_16x16x32_bf16(ah[mi], bl[ni], acc[mi][ni], 0, 0, 0);
            }
        __syncthreads();
    }

    float L   = lnv[64];
    float thr = lnv[65];
    #pragma unroll
    for (int mi = 0; mi < 4; ++mi) {
        int pbase = p0 + wrow * 64 + mi * 16 + l4 * 4;
        if (pbase >= NP) continue;
        #pragma unroll
        for (int ni = 0; ni < 2; ++ni) {
            int j = j0 + wcol * 32 + ni * 16 + l15;
            float4 cin4 = *(const float4*)&Cin[((size_t)b * JNT + j) * NPP + pbase];
            float cinv[4] = {cin4.x, cin4.y, cin4.z, cin4.w};
            float po[4];
            #pragma unroll
            for (int r = 0; r < 4; ++r) {
                int p = pbase + r;
                if (p >= NP) { po[r] = 0.0f; continue; }
                size_t ci = ((size_t)b * NP + p) * JNT + j;
                float dtyv = dty[ci];
                float ccv  = Ccur[ci];
                float g  = acc[mi][ni][r] - dtyv;
                float v  = cinv[r] - L * g;
                float a  = fabsf(v) - thr;
                float st = (a > 0.0f) ? copysignf(a, v) : 0.0f;
                Ccur[ci] = st;
                po[r] = st + tconst * (st - ccv);
            }
            size_t co = ((size_t)b * JNT + j) * NPP + pbase;
            if (pbase + 3 < NP) {
                *(float4*)&Cout[co] = make_float4(po[0], po[1], po[2], po[3]);
            } else {
                #pragma unroll
                for (int r = 0; r < 4; ++r)
                    if (pbase + r < NP) Cout[co + r] = po[r];
            }
        }
    }
}

// Y[b,t,j] = sum_p D_raw[t,p] * C[b,p,j].
__global__ __launch_bounds__(256) void ypred_kernel(const float* __restrict__ ws_c,
                                                    const float* __restrict__ C,
                                                    float* __restrict__ Y) {
    __shared__ float As[32][64];
    __shared__ float Bs[32][64];
    int tid = threadIdx.x;
    int j0 = blockIdx.x * 64, b = blockIdx.y;
    const float* DrawT = ws_c + O_DRAWT;
    float acc[4][4] = {};
    int ty = tid >> 4, tx = tid & 15;
    for (int kc = 0; kc < 17; kc++) {
        int p0 = kc * 32;
        #pragma unroll
        for (int i = 0; i < 2; i++) {
            int lin = i * 256 + tid;
            int kp = lin >> 4, tg = lin & 15;
            float4 v = make_float4(0, 0, 0, 0);
            int p = p0 + kp;
            if (p < NP) v = *(const float4*)&DrawT[(size_t)p * 64 + tg * 4];
            *(float4*)&As[kp][tg * 4] = v;
        }
        #pragma unroll
        for (int i = 0; i < 2; i++) {
            int lin = i * 256 + tid;
            int kp = lin >> 4, jg = lin & 15;
            float4 v = make_float4(0, 0, 0, 0);
            int p = p0 + kp;
            if (p < NP) v = *(const float4*)&C[((size_t)b * NP + p) * JNT + j0 + jg * 4];
            *(float4*)&Bs[kp][jg * 4] = v;
        }
        __syncthreads();
        #pragma unroll
        for (int k = 0; k < 32; k++) {
            float4 a  = *(float4*)&As[k][ty * 4];
            float4 bv = *(float4*)&Bs[k][tx * 4];
            float av[4] = {a.x, a.y, a.z, a.w};
            float bw[4] = {bv.x, bv.y, bv.z, bv.w};
            #pragma unroll
            for (int i2 = 0; i2 < 4; i2++)
                #pragma unroll
                for (int jj = 0; jj < 4; jj++)
                    acc[i2][jj] = fmaf(av[i2], bw[jj], acc[i2][jj]);
        }
        __syncthreads();
    }
    #pragma unroll
    for (int i2 = 0; i2 < 4; i2++) {
        int t = ty * 4 + i2;
        size_t base = ((size_t)b * T_LEN + t) * JNT + j0 + tx * 4;
        *(float4*)&Y[base] = make_float4(acc[i2][0], acc[i2][1], acc[i2][2], acc[i2][3]);
    }
}

extern "C" void kernel_launch(void* const* d_in, const int* in_sizes, int n_in,
                              void* d_out, int out_size, void* d_ws, size_t ws_size,
                              hipStream_t stream) {
    const float* y  = (const float*)d_in[0];
    const float* r  = (const float*)d_in[1];
    const float* th = (const float*)d_in[2];
    float* ws   = (float*)d_ws;
    float* out  = (float*)d_out;
    float* dtd  = out;                 // [640][544] scratch in Y region
    float* ln   = out + LN_OFF;        // 64 partials + L + thr
    float* Ccur = out + Y_ELEMS;       // C_pred region = C_curr

    hipMemsetAsync(out,         0, (size_t)(DTD_F + 68) * 4, stream);   // DtD + ln
    hipMemsetAsync(ws + O_D,    0, (size_t)(T_LEN * NPP) * 4, stream);  // D pads
    hipMemsetAsync(ws + O_CA,   0, (size_t)CP_ELEMS * 4, stream);
    hipMemsetAsync(ws + O_CB,   0, (size_t)CP_ELEMS * 4, stream);
    hipMemsetAsync(Ccur,        0, (size_t)C_ELEMS * 4, stream);

    build_D<<<NP, 64, 0, stream>>>(r, th, ws);
    dtd_kernel<<<(NP * NP + 255) / 256, 256, 0, stream>>>(ws, dtd);
    lnorm1<<<64, 256, 0, stream>>>(dtd, ln);
    lnorm2<<<1, 64, 0, stream>>>(ln);
    dty_kernel<<<dim3(9, 8, 32), 256, 0, stream>>>(y, ws);

    float* CA = ws + O_CA;
    float* CB = ws + O_CB;
    float t_prev = 1.0f;
    for (int it = 0; it < NITER; ++it) {
        float t_next = (1.0f + sqrtf(1.0f + 4.0f * t_prev * t_prev)) * 0.5f;
        float tconst = (t_prev - 1.0f) / t_next;
        const float* Cin = (it & 1) ? CB : CA;
        float*       Cot = (it & 1) ? CA : CB;
        fista_mfma<<<dim3(5, 8, 32), 256, 0, stream>>>(dtd, ln, ws + O_DTY,
                                                       Cin, Cot, Ccur, tconst);
        t_prev = t_next;
    }

    ypred_kernel<<<dim3(8, 32), 256, 0, stream>>>(ws, Ccur, out);
}

// Round 3
// 1948.138 us; speedup vs baseline: 2.4399x; 1.7661x over previous
//
#include <hip/hip_runtime.h>
#include <cmath>

#define NP    513
#define NPP   516
#define T_LEN 64
#define JNT   512
#define NITER 30

// d_out scratch (floats): [0..348160) DtD fp32 [640][544]; [348160..348226) lnorm.
// Both overwritten later by ypred (Y region = 1,048,576 floats).
#define DTD_STR  544
#define DTD_F    (640 * DTD_STR)
#define LN_OFF   DTD_F
#define Y_ELEMS  1048576

// ws layout (floats)
#define O_DRAWT 0                          // [513][64] f32
#define O_D     32832                      // [64][516] f32 (pad cols zeroed)
#define O_DTY   65856                      // LdtY [32][512][544] f32 (L-scaled, j-major)
#define O_AH    8978752                    // Ahg [576][560] bf16 (as ushort)
#define O_AL    9140032                    // Alg [576][560] bf16

#define MP    576       // padded M (p)
#define ASTR  560       // Ahg/Alg row stride (bf16 elems)
#define PSTR  544       // LdtY p-stride
#define LDSTR 552       // LDS B row stride (bf16 elems)
#define LDSJ  64
#define LDS_BYTES (LDSJ * LDSTR * 2 * 2)   // Bh + Bl = 141312

typedef short short8 __attribute__((ext_vector_type(8)));
typedef float f32x4  __attribute__((ext_vector_type(4)));

__device__ __forceinline__ unsigned short f2bf(float f) {
    unsigned u = __float_as_uint(f);
    return (unsigned short)((u + 0x7fffu + ((u >> 16) & 1u)) >> 16);
}
__device__ __forceinline__ float bf2f(unsigned short h) {
    return __uint_as_float((unsigned)h << 16);
}
__device__ __forceinline__ void split2(float f, unsigned short& h, unsigned short& l) {
    unsigned short hs = f2bf(f);
    h = hs;
    l = f2bf(f - bf2f(hs));
}

__global__ void build_D(const float* __restrict__ r, const float* __restrict__ th,
                        float* __restrict__ ws) {
    int p = blockIdx.x;          // 0..512
    int t = threadIdx.x;         // 0..63
    float val;
    if (p == 0) {
        val = 1.0f;
    } else if (p <= 256) {
        int n = p - 1;
        val = powf(r[n], (float)t) * cosf((float)t * th[n]);
    } else {
        int n = p - 257;
        val = powf(r[n], (float)t) * sinf((float)t * th[n]);
    }
    float s = val * val;
    #pragma unroll
    for (int off = 32; off; off >>= 1) s += __shfl_xor(s, off);
    float norm = sqrtf(s);
    ws[O_DRAWT + p * 64 + t] = val;
    ws[O_D + t * NPP + p]    = val / norm;
}

__global__ void dtd_kernel(const float* __restrict__ ws, float* __restrict__ dtd_out) {
    int idx = blockIdx.x * 256 + threadIdx.x;
    if (idx >= NP * NP) return;
    int p = idx / NP, q = idx % NP;
    const float* D = ws + O_D;
    float s = 0.0f;
    #pragma unroll 8
    for (int t = 0; t < T_LEN; t++) s = fmaf(D[t * NPP + p], D[t * NPP + q], s);
    dtd_out[(size_t)p * DTD_STR + q] = s;
}

__global__ __launch_bounds__(256) void lnorm1(const float* __restrict__ dtd_s,
                                              float* __restrict__ ln) {
    __shared__ float sm[256];
    int tid = threadIdx.x;
    size_t base = (size_t)blockIdx.x * 5440;
    float acc = 0.0f;
    for (int i = tid; i < 1360; i += 256) {
        float4 v = *(const float4*)&dtd_s[base + (size_t)i * 4];
        acc += v.x * v.x + v.y * v.y + v.z * v.z + v.w * v.w;
    }
    sm[tid] = acc; __syncthreads();
    for (int off = 128; off; off >>= 1) {
        if (tid < off) sm[tid] += sm[tid + off];
        __syncthreads();
    }
    if (tid == 0) ln[blockIdx.x] = sm[0];
}

__global__ void lnorm2(float* __restrict__ ln) {
    int lane = threadIdx.x;      // 64
    float v = ln[lane];
    #pragma unroll
    for (int off = 32; off; off >>= 1) v += __shfl_xor(v, off);
    if (lane == 0) {
        float L = 1.0f / sqrtf(v);
        ln[64] = L;
        ln[65] = L * 0.1f;
    }
}

// split DtD fp32 -> hi/lo bf16, padded [576][560]
__global__ void dtd_split(const float* __restrict__ dtd_s,
                          unsigned short* __restrict__ Ahg,
                          unsigned short* __restrict__ Alg) {
    int idx = blockIdx.x * 256 + threadIdx.x;
    if (idx >= MP * ASTR) return;
    int m = idx / ASTR, k = idx % ASTR;
    float v = (k < DTD_STR) ? dtd_s[(size_t)m * DTD_STR + k] : 0.0f;
    unsigned short h, l;
    split2(v, h, l);
    Ahg[idx] = h;
    Alg[idx] = l;
}

// LdtY[b][j][p] = L * sum_t D[t,p]*y[b,t,j], p-stride 544 (rows >=513 are zero)
__global__ __launch_bounds__(256) void dty_kernel(const float* __restrict__ y,
                                                  const float* __restrict__ ws,
                                                  const float* __restrict__ lnv,
                                                  float* __restrict__ ldty) {
    __shared__ float As[T_LEN][64];
    __shared__ float Bs[T_LEN][64];
    int tid = threadIdx.x;
    int p0 = blockIdx.x * 64, j0 = blockIdx.y * 64, b = blockIdx.z;
    const float* D = ws + O_D;
    #pragma unroll
    for (int i = 0; i < 4; i++) {
        int lin = i * 256 + tid;
        int kt = lin >> 4, pg = lin & 15;
        float4 v = make_float4(0, 0, 0, 0);
        int pp = p0 + pg * 4;
        if (pp < NPP) v = *(const float4*)&D[kt * NPP + pp];
        *(float4*)&As[kt][pg * 4] = v;
    }
    #pragma unroll
    for (int i = 0; i < 4; i++) {
        int lin = i * 256 + tid;
        int kt = lin >> 4, jg = lin & 15;
        *(float4*)&Bs[kt][jg * 4] =
            *(const float4*)&y[((size_t)b * T_LEN + kt) * JNT + j0 + jg * 4];
    }
    __syncthreads();
    int ty = tid >> 4, tx = tid & 15;
    float acc[4][4] = {};
    #pragma unroll 8
    for (int k = 0; k < T_LEN; k++) {
        float4 a  = *(float4*)&As[k][ty * 4];
        float4 bv = *(float4*)&Bs[k][tx * 4];
        float av[4] = {a.x, a.y, a.z, a.w};
        float bw[4] = {bv.x, bv.y, bv.z, bv.w};
        #pragma unroll
        for (int i2 = 0; i2 < 4; i2++)
            #pragma unroll
            for (int jj = 0; jj < 4; jj++)
                acc[i2][jj] = fmaf(av[i2], bw[jj], acc[i2][jj]);
    }
    float L = lnv[64];
    int p = p0 + ty * 4;
    if (p < PSTR) {
        #pragma unroll
        for (int jj = 0; jj < 4; jj++) {
            int j = j0 + tx * 4 + jj;
            float4 o = make_float4(acc[0][jj] * L, acc[1][jj] * L,
                                   acc[2][jj] * L, acc[3][jj] * L);
            *(float4*)&ldty[((size_t)b * JNT + j) * PSTR + p] = o;
        }
    }
}

// Persistent FISTA: all 30 iterations. One block per 64 columns (grid 8x32 = 256).
// State: C_prev as split bf16 hi/lo in LDS ([64 j][552 q]); C_curr in registers.
// Matmul: acc = DtD @ C_prev via 3-product bf16 split; A streamed from L2.
__global__ __launch_bounds__(512, 2) void fista_persist(
    const unsigned short* __restrict__ Ahg,
    const unsigned short* __restrict__ Alg,
    const float* __restrict__ ldty,     // [32][512][544] pre-scaled by L
    const float* __restrict__ lnv,      // [64]=L, [65]=thr
    float* __restrict__ Cg)             // [32][513][512]
{
    extern __shared__ unsigned short smv[];
    unsigned short* BhL = smv;
    unsigned short* BlL = smv + LDSJ * LDSTR;
    int tid = threadIdx.x;
    int jb = blockIdx.x, b = blockIdx.y;
    int lane = tid & 63, wid = tid >> 6;
    int wm = wid >> 1, wn = wid & 1;
    int l15 = lane & 15, l4 = lane >> 4;
    int j0g = jb * 64;

    {   // zero LDS state
        unsigned* p32 = (unsigned*)smv;
        for (int i = tid; i < LDS_BYTES / 4; i += 512) p32[i] = 0u;
    }
    __syncthreads();

    float L = lnv[64], thr = lnv[65];

    f32x4 ccur[9][2];
    #pragma unroll
    for (int mi = 0; mi < 9; ++mi)
        #pragma unroll
        for (int ni = 0; ni < 2; ++ni) ccur[mi][ni] = (f32x4){0, 0, 0, 0};

    float t_prev = 1.0f;

    for (int it = 0; it < NITER; ++it) {
        float t_next = (1.0f + sqrtf(1.0f + 4.0f * t_prev * t_prev)) * 0.5f;
        float tc = (t_prev - 1.0f) / t_next;
        t_prev = t_next;

        f32x4 acc[9][2];
        #pragma unroll
        for (int mi = 0; mi < 9; ++mi)
            #pragma unroll
            for (int ni = 0; ni < 2; ++ni) acc[mi][ni] = (f32x4){0, 0, 0, 0};

        #pragma unroll 1
        for (int kc = 0; kc < 17; ++kc) {
            int q0 = kc * 32;
            short8 bh[2], bl[2];
            #pragma unroll
            for (int ni = 0; ni < 2; ++ni) {
                int off = (wn * 32 + ni * 16 + l15) * LDSTR + q0 + l4 * 8;
                bh[ni] = *(const short8*)&BhL[off];
                bl[ni] = *(const short8*)&BlL[off];
            }
            #pragma unroll
            for (int mi = 0; mi < 9; ++mi) {
                int m = wm * 144 + mi * 16 + l15;
                size_t ao = (size_t)m * ASTR + q0 + l4 * 8;
                short8 ah = *(const short8*)&Ahg[ao];
                short8 al = *(const short8*)&Alg[ao];
                #pragma unroll
                for (int ni = 0; ni < 2; ++ni) {
                    acc[mi][ni] = __builtin_amdgcn_mfma_f32_16x16x32_bf16(ah, bh[ni], acc[mi][ni], 0, 0, 0);
                    acc[mi][ni] = __builtin_amdgcn_mfma_f32_16x16x32_bf16(al, bh[ni], acc[mi][ni], 0, 0, 0);
                    acc[mi][ni] = __builtin_amdgcn_mfma_f32_16x16x32_bf16(ah, bl[ni], acc[mi][ni], 0, 0, 0);
                }
            }
        }
        __syncthreads();   // all B reads done before state overwrite

        #pragma unroll
        for (int mi = 0; mi < 9; ++mi) {
            int p = wm * 144 + mi * 16 + l4 * 4;
            if (p > 512) continue;      // p quad start; 512 is the partial quad
            #pragma unroll
            for (int ni = 0; ni < 2; ++ni) {
                int jl = wn * 32 + ni * 16 + l15;
                int j  = j0g + jl;
                float4 dv = *(const float4*)&ldty[((size_t)b * JNT + j) * PSTR + p];
                float dvv[4] = {dv.x, dv.y, dv.z, dv.w};
                int lo = jl * LDSTR + p;
                ushort4 h4 = *(const ushort4*)&BhL[lo];
                ushort4 g4 = *(const ushort4*)&BlL[lo];
                unsigned short hh[4] = {h4.x, h4.y, h4.z, h4.w};
                unsigned short gg[4] = {g4.x, g4.y, g4.z, g4.w};
                unsigned short nh[4], nl[4];
                #pragma unroll
                for (int rr = 0; rr < 4; ++rr) {
                    float cp = bf2f(hh[rr]) + bf2f(gg[rr]);
                    float v  = cp - L * acc[mi][ni][rr] + dvv[rr];
                    float a  = fabsf(v) - thr;
                    float st = (a > 0.0f) ? copysignf(a, v) : 0.0f;
                    float po = st + tc * (st - ccur[mi][ni][rr]);
                    ccur[mi][ni][rr] = st;
                    split2(po, nh[rr], nl[rr]);
                }
                *(ushort4*)&BhL[lo] = make_ushort4(nh[0], nh[1], nh[2], nh[3]);
                *(ushort4*)&BlL[lo] = make_ushort4(nl[0], nl[1], nl[2], nl[3]);
            }
        }
        __syncthreads();   // state visible before next matmul
    }

    // final store: C_pred = C_curr -> [b][p][j]
    #pragma unroll
    for (int mi = 0; mi < 9; ++mi) {
        int pq = wm * 144 + mi * 16 + l4 * 4;
        if (pq > 512) continue;
        #pragma unroll
        for (int ni = 0; ni < 2; ++ni) {
            int j = j0g + wn * 32 + ni * 16 + l15;
            #pragma unroll
            for (int rr = 0; rr < 4; ++rr) {
                int p = pq + rr;
                if (p < NP) Cg[((size_t)b * NP + p) * JNT + j] = ccur[mi][ni][rr];
            }
        }
    }
}

// Y[b,t,j] = sum_p D_raw[t,p] * C[b,p,j]
__global__ __launch_bounds__(256) void ypred_kernel(const float* __restrict__ ws_c,
                                                    const float* __restrict__ C,
                                                    float* __restrict__ Y) {
    __shared__ float As[32][64];
    __shared__ float Bs[32][64];
    int tid = threadIdx.x;
    int j0 = blockIdx.x * 64, b = blockIdx.y;
    const float* DrawT = ws_c + O_DRAWT;
    float acc[4][4] = {};
    int ty = tid >> 4, tx = tid & 15;
    for (int kc = 0; kc < 17; kc++) {
        int p0 = kc * 32;
        #pragma unroll
        for (int i = 0; i < 2; i++) {
            int lin = i * 256 + tid;
            int kp = lin >> 4, tg = lin & 15;
            float4 v = make_float4(0, 0, 0, 0);
            int p = p0 + kp;
            if (p < NP) v = *(const float4*)&DrawT[(size_t)p * 64 + tg * 4];
            *(float4*)&As[kp][tg * 4] = v;
        }
        #pragma unroll
        for (int i = 0; i < 2; i++) {
            int lin = i * 256 + tid;
            int kp = lin >> 4, jg = lin & 15;
            float4 v = make_float4(0, 0, 0, 0);
            int p = p0 + kp;
            if (p < NP) v = *(const float4*)&C[((size_t)b * NP + p) * JNT + j0 + jg * 4];
            *(float4*)&Bs[kp][jg * 4] = v;
        }
        __syncthreads();
        #pragma unroll
        for (int k = 0; k < 32; k++) {
            float4 a  = *(float4*)&As[k][ty * 4];
            float4 bv = *(float4*)&Bs[k][tx * 4];
            float av[4] = {a.x, a.y, a.z, a.w};
            float bw[4] = {bv.x, bv.y, bv.z, bv.w};
            #pragma unroll
            for (int i2 = 0; i2 < 4; i2++)
                #pragma unroll
                for (int jj = 0; jj < 4; jj++)
                    acc[i2][jj] = fmaf(av[i2], bw[jj], acc[i2][jj]);
        }
        __syncthreads();
    }
    #pragma unroll
    for (int i2 = 0; i2 < 4; i2++) {
        int t = ty * 4 + i2;
        size_t base = ((size_t)b * T_LEN + t) * JNT + j0 + tx * 4;
        *(float4*)&Y[base] = make_float4(acc[i2][0], acc[i2][1], acc[i2][2], acc[i2][3]);
    }
}

extern "C" void kernel_launch(void* const* d_in, const int* in_sizes, int n_in,
                              void* d_out, int out_size, void* d_ws, size_t ws_size,
                              hipStream_t stream) {
    const float* y  = (const float*)d_in[0];
    const float* r  = (const float*)d_in[1];
    const float* th = (const float*)d_in[2];
    float* ws   = (float*)d_ws;
    float* out  = (float*)d_out;
    float* dtd  = out;                 // fp32 scratch in Y region
    float* ln   = out + LN_OFF;
    float* Cgo  = out + Y_ELEMS;       // C_pred output region
    unsigned short* Ahg = (unsigned short*)(ws + O_AH);
    unsigned short* Alg = (unsigned short*)(ws + O_AL);
    float* ldty = ws + O_DTY;

    hipMemsetAsync(out,      0, (size_t)(DTD_F + 68) * 4, stream);
    hipMemsetAsync(ws + O_D, 0, (size_t)(T_LEN * NPP) * 4, stream);

    build_D<<<NP, 64, 0, stream>>>(r, th, ws);
    dtd_kernel<<<(NP * NP + 255) / 256, 256, 0, stream>>>(ws, dtd);
    lnorm1<<<64, 256, 0, stream>>>(dtd, ln);
    lnorm2<<<1, 64, 0, stream>>>(ln);
    dty_kernel<<<dim3(9, 8, 32), 256, 0, stream>>>(y, ws, ln, ldty);
    dtd_split<<<(MP * ASTR + 255) / 256, 256, 0, stream>>>(dtd, Ahg, Alg);

    hipFuncSetAttribute((const void*)fista_persist,
                        hipFuncAttributeMaxDynamicSharedMemorySize, LDS_BYTES);
    fista_persist<<<dim3(8, 32), 512, LDS_BYTES, stream>>>(Ahg, Alg, ldty, ln, Cgo);

    ypred_kernel<<<dim3(8, 32), 256, 0, stream>>>(ws, Cgo, out);
}

// Round 4
// 1529.861 us; speedup vs baseline: 3.1070x; 1.2734x over previous
//
#include <hip/hip_runtime.h>
#include <cmath>

#define NP    513
#define NPP   516
#define T_LEN 64
#define JNT   512
#define NITER 30

// d_out scratch (floats): [0..348160) DtD fp32 [640][544]; [348160..348226) lnorm.
// Both overwritten later by ypred (Y region = 1,048,576 floats).
#define DTD_STR  544
#define DTD_F    (640 * DTD_STR)
#define LN_OFF   DTD_F
#define Y_ELEMS  1048576

// ws layout (floats)
#define O_DRAWT 0                          // [513][64] f32
#define O_D     32832                      // [64][516] f32 (pad cols zeroed)
#define O_DTY   65856                      // LdtY [32][512][544] f32 (L-scaled, j-major)
#define O_AH    8978752                    // Ahg [576][560] bf16 (as ushort)
#define O_AL    9140032                    // Alg [576][560] bf16

#define MP    576       // padded M (p)
#define ASTR  560       // Ahg/Alg row stride (bf16 elems)
#define PSTR  544       // LdtY p-stride
#define LDSTR 552       // LDS B row stride (bf16 elems)
#define LDSJ  64
#define LDS_BYTES (LDSJ * LDSTR * 2 * 2)   // Bh + Bl = 141312

typedef short short8 __attribute__((ext_vector_type(8)));
typedef float f32x4  __attribute__((ext_vector_type(4)));

__device__ __forceinline__ unsigned short f2bf(float f) {
    unsigned u = __float_as_uint(f);
    return (unsigned short)((u + 0x7fffu + ((u >> 16) & 1u)) >> 16);
}
__device__ __forceinline__ float bf2f(unsigned short h) {
    return __uint_as_float((unsigned)h << 16);
}
__device__ __forceinline__ void split2(float f, unsigned short& h, unsigned short& l) {
    unsigned short hs = f2bf(f);
    h = hs;
    l = f2bf(f - bf2f(hs));
}

__global__ void build_D(const float* __restrict__ r, const float* __restrict__ th,
                        float* __restrict__ ws) {
    int p = blockIdx.x;          // 0..512
    int t = threadIdx.x;         // 0..63
    float val;
    if (p == 0) {
        val = 1.0f;
    } else if (p <= 256) {
        int n = p - 1;
        val = powf(r[n], (float)t) * cosf((float)t * th[n]);
    } else {
        int n = p - 257;
        val = powf(r[n], (float)t) * sinf((float)t * th[n]);
    }
    float s = val * val;
    #pragma unroll
    for (int off = 32; off; off >>= 1) s += __shfl_xor(s, off);
    float norm = sqrtf(s);
    ws[O_DRAWT + p * 64 + t] = val;
    ws[O_D + t * NPP + p]    = val / norm;
}

__global__ void dtd_kernel(const float* __restrict__ ws, float* __restrict__ dtd_out) {
    int idx = blockIdx.x * 256 + threadIdx.x;
    if (idx >= NP * NP) return;
    int p = idx / NP, q = idx % NP;
    const float* D = ws + O_D;
    float s = 0.0f;
    #pragma unroll 8
    for (int t = 0; t < T_LEN; t++) s = fmaf(D[t * NPP + p], D[t * NPP + q], s);
    dtd_out[(size_t)p * DTD_STR + q] = s;
}

__global__ __launch_bounds__(256) void lnorm1(const float* __restrict__ dtd_s,
                                              float* __restrict__ ln) {
    __shared__ float sm[256];
    int tid = threadIdx.x;
    size_t base = (size_t)blockIdx.x * 5440;
    float acc = 0.0f;
    for (int i = tid; i < 1360; i += 256) {
        float4 v = *(const float4*)&dtd_s[base + (size_t)i * 4];
        acc += v.x * v.x + v.y * v.y + v.z * v.z + v.w * v.w;
    }
    sm[tid] = acc; __syncthreads();
    for (int off = 128; off; off >>= 1) {
        if (tid < off) sm[tid] += sm[tid + off];
        __syncthreads();
    }
    if (tid == 0) ln[blockIdx.x] = sm[0];
}

__global__ void lnorm2(float* __restrict__ ln) {
    int lane = threadIdx.x;      // 64
    float v = ln[lane];
    #pragma unroll
    for (int off = 32; off; off >>= 1) v += __shfl_xor(v, off);
    if (lane == 0) {
        float L = 1.0f / sqrtf(v);
        ln[64] = L;
        ln[65] = L * 0.1f;
    }
}

// split DtD fp32 -> hi/lo bf16, padded [576][560]
__global__ void dtd_split(const float* __restrict__ dtd_s,
                          unsigned short* __restrict__ Ahg,
                          unsigned short* __restrict__ Alg) {
    int idx = blockIdx.x * 256 + threadIdx.x;
    if (idx >= MP * ASTR) return;
    int m = idx / ASTR, k = idx % ASTR;
    float v = (k < DTD_STR) ? dtd_s[(size_t)m * DTD_STR + k] : 0.0f;
    unsigned short h, l;
    split2(v, h, l);
    Ahg[idx] = h;
    Alg[idx] = l;
}

// LdtY[b][j][p] = L * sum_t D[t,p]*y[b,t,j], p-stride 544 (rows >=513 are zero)
__global__ __launch_bounds__(256) void dty_kernel(const float* __restrict__ y,
                                                  const float* __restrict__ ws,
                                                  const float* __restrict__ lnv,
                                                  float* __restrict__ ldty) {
    __shared__ float As[T_LEN][64];
    __shared__ float Bs[T_LEN][64];
    int tid = threadIdx.x;
    int p0 = blockIdx.x * 64, j0 = blockIdx.y * 64, b = blockIdx.z;
    const float* D = ws + O_D;
    #pragma unroll
    for (int i = 0; i < 4; i++) {
        int lin = i * 256 + tid;
        int kt = lin >> 4, pg = lin & 15;
        float4 v = make_float4(0, 0, 0, 0);
        int pp = p0 + pg * 4;
        if (pp < NPP) v = *(const float4*)&D[kt * NPP + pp];
        *(float4*)&As[kt][pg * 4] = v;
    }
    #pragma unroll
    for (int i = 0; i < 4; i++) {
        int lin = i * 256 + tid;
        int kt = lin >> 4, jg = lin & 15;
        *(float4*)&Bs[kt][jg * 4] =
            *(const float4*)&y[((size_t)b * T_LEN + kt) * JNT + j0 + jg * 4];
    }
    __syncthreads();
    int ty = tid >> 4, tx = tid & 15;
    float acc[4][4] = {};
    #pragma unroll 8
    for (int k = 0; k < T_LEN; k++) {
        float4 a  = *(float4*)&As[k][ty * 4];
        float4 bv = *(float4*)&Bs[k][tx * 4];
        float av[4] = {a.x, a.y, a.z, a.w};
        float bw[4] = {bv.x, bv.y, bv.z, bv.w};
        #pragma unroll
        for (int i2 = 0; i2 < 4; i2++)
            #pragma unroll
            for (int jj = 0; jj < 4; jj++)
                acc[i2][jj] = fmaf(av[i2], bw[jj], acc[i2][jj]);
    }
    float L = lnv[64];
    int p = p0 + ty * 4;
    if (p < PSTR) {
        #pragma unroll
        for (int jj = 0; jj < 4; jj++) {
            int j = j0 + tx * 4 + jj;
            float4 o = make_float4(acc[0][jj] * L, acc[1][jj] * L,
                                   acc[2][jj] * L, acc[3][jj] * L);
            *(float4*)&ldty[((size_t)b * JNT + j) * PSTR + p] = o;
        }
    }
}

// Persistent FISTA: all 30 iterations. One block per 64 columns (grid 8x32 = 256).
// State: C_prev as split bf16 hi/lo in LDS; C_curr and L*DtY in registers.
// A (DtD split hi/lo bf16) streamed from L2 (1.3 MB, resident now that ldty
// no longer flows through L2 every iteration).
__global__ __launch_bounds__(512, 2) void fista_persist(
    const unsigned short* __restrict__ Ahg,
    const unsigned short* __restrict__ Alg,
    const float* __restrict__ ldty,     // [32][512][544] pre-scaled by L
    const float* __restrict__ lnv,      // [64]=L, [65]=thr
    float* __restrict__ Cg)             // [32][513][512]
{
    extern __shared__ unsigned short smv[];
    unsigned short* BhL = smv;
    unsigned short* BlL = smv + LDSJ * LDSTR;
    int tid = threadIdx.x;
    int jb = blockIdx.x, b = blockIdx.y;
    int lane = tid & 63, wid = tid >> 6;
    int wm = wid >> 1, wn = wid & 1;
    int l15 = lane & 15, l4 = lane >> 4;
    int j0g = jb * 64;

    {   // zero LDS state
        unsigned* p32 = (unsigned*)smv;
        for (int i = tid; i < LDS_BYTES / 4; i += 512) p32[i] = 0u;
    }

    float L = lnv[64], thr = lnv[65];

    // preload constant L*DtY fragments and init C_curr (both in registers)
    f32x4 ldtyR[9][2];
    f32x4 ccur[9][2];
    #pragma unroll
    for (int mi = 0; mi < 9; ++mi) {
        int p = wm * 144 + mi * 16 + l4 * 4;
        #pragma unroll
        for (int ni = 0; ni < 2; ++ni) {
            ccur[mi][ni] = (f32x4){0, 0, 0, 0};
            ldtyR[mi][ni] = (f32x4){0, 0, 0, 0};
            if (p <= 512) {
                int j = j0g + wn * 32 + ni * 16 + l15;
                float4 v = *(const float4*)&ldty[((size_t)b * JNT + j) * PSTR + p];
                ldtyR[mi][ni] = (f32x4){v.x, v.y, v.z, v.w};
            }
        }
    }
    __syncthreads();

    float t_prev = 1.0f;

    for (int it = 0; it < NITER; ++it) {
        float t_next = (1.0f + sqrtf(1.0f + 4.0f * t_prev * t_prev)) * 0.5f;
        float tc = (t_prev - 1.0f) / t_next;
        t_prev = t_next;

        f32x4 acc[9][2];
        #pragma unroll
        for (int mi = 0; mi < 9; ++mi)
            #pragma unroll
            for (int ni = 0; ni < 2; ++ni) acc[mi][ni] = (f32x4){0, 0, 0, 0};

        if (it > 0) {   // it==0: C_prev == 0 -> matmul is zero
            #pragma unroll 1
            for (int kc = 0; kc < 17; ++kc) {
                int q0 = kc * 32;
                short8 bh[2], bl[2];
                #pragma unroll
                for (int ni = 0; ni < 2; ++ni) {
                    int off = (wn * 32 + ni * 16 + l15) * LDSTR + q0 + l4 * 8;
                    bh[ni] = *(const short8*)&BhL[off];
                    bl[ni] = *(const short8*)&BlL[off];
                }
                #pragma unroll
                for (int mi = 0; mi < 9; ++mi) {
                    int m = wm * 144 + mi * 16 + l15;
                    size_t ao = (size_t)m * ASTR + q0 + l4 * 8;
                    short8 ah = *(const short8*)&Ahg[ao];
                    short8 al = *(const short8*)&Alg[ao];
                    #pragma unroll
                    for (int ni = 0; ni < 2; ++ni) {
                        acc[mi][ni] = __builtin_amdgcn_mfma_f32_16x16x32_bf16(ah, bh[ni], acc[mi][ni], 0, 0, 0);
                        acc[mi][ni] = __builtin_amdgcn_mfma_f32_16x16x32_bf16(al, bh[ni], acc[mi][ni], 0, 0, 0);
                        acc[mi][ni] = __builtin_amdgcn_mfma_f32_16x16x32_bf16(ah, bl[ni], acc[mi][ni], 0, 0, 0);
                    }
                }
            }
        }
        __syncthreads();   // all B reads done before state overwrite

        #pragma unroll
        for (int mi = 0; mi < 9; ++mi) {
            int p = wm * 144 + mi * 16 + l4 * 4;
            if (p > 512) continue;      // p quad start; 512 is the partial quad
            #pragma unroll
            for (int ni = 0; ni < 2; ++ni) {
                int jl = wn * 32 + ni * 16 + l15;
                int lo = jl * LDSTR + p;
                ushort4 h4 = *(const ushort4*)&BhL[lo];
                ushort4 g4 = *(const ushort4*)&BlL[lo];
                unsigned short hh[4] = {h4.x, h4.y, h4.z, h4.w};
                unsigned short gg[4] = {g4.x, g4.y, g4.z, g4.w};
                unsigned short nh[4], nl[4];
                #pragma unroll
                for (int rr = 0; rr < 4; ++rr) {
                    float cp = bf2f(hh[rr]) + bf2f(gg[rr]);
                    float v  = cp - L * acc[mi][ni][rr] + ldtyR[mi][ni][rr];
                    float a  = fabsf(v) - thr;
                    float st = (a > 0.0f) ? copysignf(a, v) : 0.0f;
                    float po = st + tc * (st - ccur[mi][ni][rr]);
                    ccur[mi][ni][rr] = st;
                    split2(po, nh[rr], nl[rr]);
                }
                *(ushort4*)&BhL[lo] = make_ushort4(nh[0], nh[1], nh[2], nh[3]);
                *(ushort4*)&BlL[lo] = make_ushort4(nl[0], nl[1], nl[2], nl[3]);
            }
        }
        __syncthreads();   // state visible before next matmul
    }

    // final store: C_pred = C_curr -> [b][p][j]
    #pragma unroll
    for (int mi = 0; mi < 9; ++mi) {
        int pq = wm * 144 + mi * 16 + l4 * 4;
        if (pq > 512) continue;
        #pragma unroll
        for (int ni = 0; ni < 2; ++ni) {
            int j = j0g + wn * 32 + ni * 16 + l15;
            #pragma unroll
            for (int rr = 0; rr < 4; ++rr) {
                int p = pq + rr;
                if (p < NP) Cg[((size_t)b * NP + p) * JNT + j] = ccur[mi][ni][rr];
            }
        }
    }
}

// Y[b,t,j] = sum_p D_raw[t,p] * C[b,p,j]
__global__ __launch_bounds__(256) void ypred_kernel(const float* __restrict__ ws_c,
                                                    const float* __restrict__ C,
                                                    float* __restrict__ Y) {
    __shared__ float As[32][64];
    __shared__ float Bs[32][64];
    int tid = threadIdx.x;
    int j0 = blockIdx.x * 64, b = blockIdx.y;
    const float* DrawT = ws_c + O_DRAWT;
    float acc[4][4] = {};
    int ty = tid >> 4, tx = tid & 15;
    for (int kc = 0; kc < 17; kc++) {
        int p0 = kc * 32;
        #pragma unroll
        for (int i = 0; i < 2; i++) {
            int lin = i * 256 + tid;
            int kp = lin >> 4, tg = lin & 15;
            float4 v = make_float4(0, 0, 0, 0);
            int p = p0 + kp;
            if (p < NP) v = *(const float4*)&DrawT[(size_t)p * 64 + tg * 4];
            *(float4*)&As[kp][tg * 4] = v;
        }
        #pragma unroll
        for (int i = 0; i < 2; i++) {
            int lin = i * 256 + tid;
            int kp = lin >> 4, jg = lin & 15;
            float4 v = make_float4(0, 0, 0, 0);
            int p = p0 + kp;
            if (p < NP) v = *(const float4*)&C[((size_t)b * NP + p) * JNT + j0 + jg * 4];
            *(float4*)&Bs[kp][jg * 4] = v;
        }
        __syncthreads();
        #pragma unroll
        for (int k = 0; k < 32; k++) {
            float4 a  = *(float4*)&As[k][ty * 4];
            float4 bv = *(float4*)&Bs[k][tx * 4];
            float av[4] = {a.x, a.y, a.z, a.w};
            float bw[4] = {bv.x, bv.y, bv.z, bv.w};
            #pragma unroll
            for (int i2 = 0; i2 < 4; i2++)
                #pragma unroll
                for (int jj = 0; jj < 4; jj++)
                    acc[i2][jj] = fmaf(av[i2], bw[jj], acc[i2][jj]);
        }
        __syncthreads();
    }
    #pragma unroll
    for (int i2 = 0; i2 < 4; i2++) {
        int t = ty * 4 + i2;
        size_t base = ((size_t)b * T_LEN + t) * JNT + j0 + tx * 4;
        *(float4*)&Y[base] = make_float4(acc[i2][0], acc[i2][1], acc[i2][2], acc[i2][3]);
    }
}

extern "C" void kernel_launch(void* const* d_in, const int* in_sizes, int n_in,
                              void* d_out, int out_size, void* d_ws, size_t ws_size,
                              hipStream_t stream) {
    const float* y  = (const float*)d_in[0];
    const float* r  = (const float*)d_in[1];
    const float* th = (const float*)d_in[2];
    float* ws   = (float*)d_ws;
    float* out  = (float*)d_out;
    float* dtd  = out;                 // fp32 scratch in Y region
    float* ln   = out + LN_OFF;
    float* Cgo  = out + Y_ELEMS;       // C_pred output region
    unsigned short* Ahg = (unsigned short*)(ws + O_AH);
    unsigned short* Alg = (unsigned short*)(ws + O_AL);
    float* ldty = ws + O_DTY;

    hipMemsetAsync(out,      0, (size_t)(DTD_F + 68) * 4, stream);
    hipMemsetAsync(ws + O_D, 0, (size_t)(T_LEN * NPP) * 4, stream);

    build_D<<<NP, 64, 0, stream>>>(r, th, ws);
    dtd_kernel<<<(NP * NP + 255) / 256, 256, 0, stream>>>(ws, dtd);
    lnorm1<<<64, 256, 0, stream>>>(dtd, ln);
    lnorm2<<<1, 64, 0, stream>>>(ln);
    dty_kernel<<<dim3(9, 8, 32), 256, 0, stream>>>(y, ws, ln, ldty);
    dtd_split<<<(MP * ASTR + 255) / 256, 256, 0, stream>>>(dtd, Ahg, Alg);

    hipFuncSetAttribute((const void*)fista_persist,
                        hipFuncAttributeMaxDynamicSharedMemorySize, LDS_BYTES);
    fista_persist<<<dim3(8, 32), 512, LDS_BYTES, stream>>>(Ahg, Alg, ldty, ln, Cgo);

    ypred_kernel<<<dim3(8, 32), 256, 0, stream>>>(ws, Cgo, out);
}

// Round 5
// 1084.993 us; speedup vs baseline: 4.3810x; 1.4100x over previous
//
#include <hip/hip_runtime.h>
#include <cmath>

#define NP    513
#define NPP   516
#define T_LEN 64
#define JNT   512
#define NITER 30

// d_out scratch (floats): [0..348160) DtD fp32 [640][544]; [348160..348226) lnorm.
// Both overwritten later by ypred (Y region = 1,048,576 floats).
#define DTD_STR  544
#define DTD_F    (640 * DTD_STR)
#define LN_OFF   DTD_F
#define Y_ELEMS  1048576

// ws layout (floats)
#define O_DRAWT 0                          // [513][64] f32
#define O_D     32832                      // [64][516] f32 (pad cols zeroed)
#define O_DTY   65856                      // LdtY [32][512][544] f32 (L-scaled, j-major)
#define O_AH    8978752                    // Ahg k-major [68][560][8] bf16
#define O_AL    9131072                    // Alg k-major [68][560][8] bf16

#define MPAD  560       // padded M rows in A (7 waves x 80)
#define AKSUB 68        // 544/8 k-subchunks
#define PSTR  544       // LdtY p-stride
#define LDSTR 552       // LDS B row stride (bf16 elems)
#define LDSJ  32
#define LDS_BYTES (LDSJ * LDSTR * 2 * 2)   // Bh + Bl = 70656

typedef short short8 __attribute__((ext_vector_type(8)));
typedef float f32x4  __attribute__((ext_vector_type(4)));

__device__ __forceinline__ unsigned short f2bf(float f) {
    unsigned u = __float_as_uint(f);
    return (unsigned short)((u + 0x7fffu + ((u >> 16) & 1u)) >> 16);
}
__device__ __forceinline__ float bf2f(unsigned short h) {
    return __uint_as_float((unsigned)h << 16);
}
__device__ __forceinline__ void split2(float f, unsigned short& h, unsigned short& l) {
    unsigned short hs = f2bf(f);
    h = hs;
    l = f2bf(f - bf2f(hs));
}

__global__ void build_D(const float* __restrict__ r, const float* __restrict__ th,
                        float* __restrict__ ws) {
    int p = blockIdx.x;          // 0..512
    int t = threadIdx.x;         // 0..63
    float val;
    if (p == 0) {
        val = 1.0f;
    } else if (p <= 256) {
        int n = p - 1;
        val = powf(r[n], (float)t) * cosf((float)t * th[n]);
    } else {
        int n = p - 257;
        val = powf(r[n], (float)t) * sinf((float)t * th[n]);
    }
    float s = val * val;
    #pragma unroll
    for (int off = 32; off; off >>= 1) s += __shfl_xor(s, off);
    float norm = sqrtf(s);
    ws[O_DRAWT + p * 64 + t] = val;
    ws[O_D + t * NPP + p]    = val / norm;
}

__global__ void dtd_kernel(const float* __restrict__ ws, float* __restrict__ dtd_out) {
    int idx = blockIdx.x * 256 + threadIdx.x;
    if (idx >= NP * NP) return;
    int p = idx / NP, q = idx % NP;
    const float* D = ws + O_D;
    float s = 0.0f;
    #pragma unroll 8
    for (int t = 0; t < T_LEN; t++) s = fmaf(D[t * NPP + p], D[t * NPP + q], s);
    dtd_out[(size_t)p * DTD_STR + q] = s;
}

__global__ __launch_bounds__(256) void lnorm1(const float* __restrict__ dtd_s,
                                              float* __restrict__ ln) {
    __shared__ float sm[256];
    int tid = threadIdx.x;
    size_t base = (size_t)blockIdx.x * 5440;
    float acc = 0.0f;
    for (int i = tid; i < 1360; i += 256) {
        float4 v = *(const float4*)&dtd_s[base + (size_t)i * 4];
        acc += v.x * v.x + v.y * v.y + v.z * v.z + v.w * v.w;
    }
    sm[tid] = acc; __syncthreads();
    for (int off = 128; off; off >>= 1) {
        if (tid < off) sm[tid] += sm[tid + off];
        __syncthreads();
    }
    if (tid == 0) ln[blockIdx.x] = sm[0];
}

__global__ void lnorm2(float* __restrict__ ln) {
    int lane = threadIdx.x;      // 64
    float v = ln[lane];
    #pragma unroll
    for (int off = 32; off; off >>= 1) v += __shfl_xor(v, off);
    if (lane == 0) {
        float L = 1.0f / sqrtf(v);
        ln[64] = L;
        ln[65] = L * 0.1f;
    }
}

// split DtD fp32 -> hi/lo bf16, k-major layout [68][560][8]
__global__ void dtd_split(const float* __restrict__ dtd_s,
                          unsigned short* __restrict__ Ahg,
                          unsigned short* __restrict__ Alg) {
    int idx = blockIdx.x * 256 + threadIdx.x;
    if (idx >= MPAD * DTD_STR) return;
    int m = idx / DTD_STR, k = idx % DTD_STR;
    float v = dtd_s[(size_t)m * DTD_STR + k];     // rows >=513 are zero
    unsigned short h, l;
    split2(v, h, l);
    size_t o = ((size_t)(k >> 3) * MPAD + m) * 8 + (k & 7);
    Ahg[o] = h;
    Alg[o] = l;
}

// LdtY[b][j][p] = L * sum_t D[t,p]*y[b,t,j], p-stride 544 (rows >=513 are zero)
__global__ __launch_bounds__(256) void dty_kernel(const float* __restrict__ y,
                                                  const float* __restrict__ ws,
                                                  const float* __restrict__ lnv,
                                                  float* __restrict__ ldty) {
    __shared__ float As[T_LEN][64];
    __shared__ float Bs[T_LEN][64];
    int tid = threadIdx.x;
    int p0 = blockIdx.x * 64, j0 = blockIdx.y * 64, b = blockIdx.z;
    const float* D = ws + O_D;
    #pragma unroll
    for (int i = 0; i < 4; i++) {
        int lin = i * 256 + tid;
        int kt = lin >> 4, pg = lin & 15;
        float4 v = make_float4(0, 0, 0, 0);
        int pp = p0 + pg * 4;
        if (pp < NPP) v = *(const float4*)&D[kt * NPP + pp];
        *(float4*)&As[kt][pg * 4] = v;
    }
    #pragma unroll
    for (int i = 0; i < 4; i++) {
        int lin = i * 256 + tid;
        int kt = lin >> 4, jg = lin & 15;
        *(float4*)&Bs[kt][jg * 4] =
            *(const float4*)&y[((size_t)b * T_LEN + kt) * JNT + j0 + jg * 4];
    }
    __syncthreads();
    int ty = tid >> 4, tx = tid & 15;
    float acc[4][4] = {};
    #pragma unroll 8
    for (int k = 0; k < T_LEN; k++) {
        float4 a  = *(float4*)&As[k][ty * 4];
        float4 bv = *(float4*)&Bs[k][tx * 4];
        float av[4] = {a.x, a.y, a.z, a.w};
        float bw[4] = {bv.x, bv.y, bv.z, bv.w};
        #pragma unroll
        for (int i2 = 0; i2 < 4; i2++)
            #pragma unroll
            for (int jj = 0; jj < 4; jj++)
                acc[i2][jj] = fmaf(av[i2], bw[jj], acc[i2][jj]);
    }
    float L = lnv[64];
    int p = p0 + ty * 4;
    if (p < PSTR) {
        #pragma unroll
        for (int jj = 0; jj < 4; jj++) {
            int j = j0 + tx * 4 + jj;
            float4 o = make_float4(acc[0][jj] * L, acc[1][jj] * L,
                                   acc[2][jj] * L, acc[3][jj] * L);
            *(float4*)&ldty[((size_t)b * JNT + j) * PSTR + p] = o;
        }
    }
}

// Persistent FISTA: all 30 iterations. 512 blocks (16 j-chunks x 32 batch),
// 448 threads = 7 waves; wave wm owns rows [wm*80, wm*80+80) x all 32 j.
// State C_prev split bf16 hi/lo in LDS; C_curr, L*DtY in registers.
// A k-major [68][560][8]: per kc ALL 10 frag loads issued before the 30 MFMAs.
__global__ __launch_bounds__(448, 2) void fista_persist(
    const unsigned short* __restrict__ Ahg,
    const unsigned short* __restrict__ Alg,
    const float* __restrict__ ldty,     // [32][512][544] pre-scaled by L
    const float* __restrict__ lnv,      // [64]=L, [65]=thr
    float* __restrict__ Cg)             // [32][513][512]
{
    extern __shared__ unsigned short smv[];
    unsigned short* BhL = smv;                    // [32][552]
    unsigned short* BlL = smv + LDSJ * LDSTR;
    int tid = threadIdx.x;
    int jb = blockIdx.x, b = blockIdx.y;
    int lane = tid & 63, wm = tid >> 6;           // wm 0..6
    int l15 = lane & 15, l4 = lane >> 4;
    int j0g = jb * 32;

    {   // zero LDS state (70656 B = 17664 dwords)
        unsigned* p32 = (unsigned*)smv;
        for (int i = tid; i < LDS_BYTES / 4; i += 448) p32[i] = 0u;
    }

    float L = lnv[64], thr = lnv[65];

    // preload constant L*DtY fragments; init C_curr (registers)
    f32x4 ldtyR[5][2];
    f32x4 ccur[5][2];
    #pragma unroll
    for (int mi = 0; mi < 5; ++mi) {
        int p = wm * 80 + mi * 16 + l4 * 4;
        #pragma unroll
        for (int ni = 0; ni < 2; ++ni) {
            ccur[mi][ni]  = (f32x4){0, 0, 0, 0};
            ldtyR[mi][ni] = (f32x4){0, 0, 0, 0};
            if (p <= 512) {
                int j = j0g + ni * 16 + l15;
                float4 v = *(const float4*)&ldty[((size_t)b * JNT + j) * PSTR + p];
                ldtyR[mi][ni] = (f32x4){v.x, v.y, v.z, v.w};
            }
        }
    }
    __syncthreads();

    float t_prev = 1.0f;

    for (int it = 0; it < NITER; ++it) {
        float t_next = (1.0f + sqrtf(1.0f + 4.0f * t_prev * t_prev)) * 0.5f;
        float tc = (t_prev - 1.0f) / t_next;
        t_prev = t_next;

        f32x4 acc[5][2];
        #pragma unroll
        for (int mi = 0; mi < 5; ++mi)
            #pragma unroll
            for (int ni = 0; ni < 2; ++ni) acc[mi][ni] = (f32x4){0, 0, 0, 0};

        if (it > 0) {   // it==0: C_prev == 0 -> matmul is zero
            #pragma unroll 1
            for (int kc = 0; kc < 17; ++kc) {
                int q0 = kc * 32;
                // B fragments from LDS
                short8 bh[2], bl[2];
                #pragma unroll
                for (int ni = 0; ni < 2; ++ni) {
                    int off = (ni * 16 + l15) * LDSTR + q0 + l4 * 8;
                    bh[ni] = *(const short8*)&BhL[off];
                    bl[ni] = *(const short8*)&BlL[off];
                }
                // A fragments: ALL loads issued before any MFMA (ILP)
                short8 ah[5], al[5];
                size_t abase = ((size_t)(kc * 4 + l4) * MPAD + wm * 80 + l15) * 8;
                #pragma unroll
                for (int mi = 0; mi < 5; ++mi)
                    ah[mi] = *(const short8*)&Ahg[abase + mi * 128];
                #pragma unroll
                for (int mi = 0; mi < 5; ++mi)
                    al[mi] = *(const short8*)&Alg[abase + mi * 128];
                #pragma unroll
                for (int mi = 0; mi < 5; ++mi)
                    #pragma unroll
                    for (int ni = 0; ni < 2; ++ni) {
                        acc[mi][ni] = __builtin_amdgcn_mfma_f32_16x16x32_bf16(ah[mi], bh[ni], acc[mi][ni], 0, 0, 0);
                        acc[mi][ni] = __builtin_amdgcn_mfma_f32_16x16x32_bf16(al[mi], bh[ni], acc[mi][ni], 0, 0, 0);
                        acc[mi][ni] = __builtin_amdgcn_mfma_f32_16x16x32_bf16(ah[mi], bl[ni], acc[mi][ni], 0, 0, 0);
                    }
            }
        }
        __syncthreads();   // all B reads done before state overwrite

        #pragma unroll
        for (int mi = 0; mi < 5; ++mi) {
            int p = wm * 80 + mi * 16 + l4 * 4;
            if (p > 512) continue;      // p quad start; 512 is the partial quad
            #pragma unroll
            for (int ni = 0; ni < 2; ++ni) {
                int jl = ni * 16 + l15;
                int lo = jl * LDSTR + p;
                ushort4 h4 = *(const ushort4*)&BhL[lo];
                ushort4 g4 = *(const ushort4*)&BlL[lo];
                unsigned short hh[4] = {h4.x, h4.y, h4.z, h4.w};
                unsigned short gg[4] = {g4.x, g4.y, g4.z, g4.w};
                unsigned short nh[4], nl[4];
                #pragma unroll
                for (int rr = 0; rr < 4; ++rr) {
                    float cp = bf2f(hh[rr]) + bf2f(gg[rr]);
                    float v  = cp - L * acc[mi][ni][rr] + ldtyR[mi][ni][rr];
                    float a  = fabsf(v) - thr;
                    float st = (a > 0.0f) ? copysignf(a, v) : 0.0f;
                    float po = st + tc * (st - ccur[mi][ni][rr]);
                    ccur[mi][ni][rr] = st;
                    split2(po, nh[rr], nl[rr]);
                }
                *(ushort4*)&BhL[lo] = make_ushort4(nh[0], nh[1], nh[2], nh[3]);
                *(ushort4*)&BlL[lo] = make_ushort4(nl[0], nl[1], nl[2], nl[3]);
            }
        }
        __syncthreads();   // state visible before next matmul
    }

    // final store: C_pred = C_curr -> [b][p][j]
    #pragma unroll
    for (int mi = 0; mi < 5; ++mi) {
        int pq = wm * 80 + mi * 16 + l4 * 4;
        if (pq > 512) continue;
        #pragma unroll
        for (int ni = 0; ni < 2; ++ni) {
            int j = j0g + ni * 16 + l15;
            #pragma unroll
            for (int rr = 0; rr < 4; ++rr) {
                int p = pq + rr;
                if (p < NP) Cg[((size_t)b * NP + p) * JNT + j] = ccur[mi][ni][rr];
            }
        }
    }
}

// Y[b,t,j] = sum_p D_raw[t,p] * C[b,p,j]
__global__ __launch_bounds__(256) void ypred_kernel(const float* __restrict__ ws_c,
                                                    const float* __restrict__ C,
                                                    float* __restrict__ Y) {
    __shared__ float As[32][64];
    __shared__ float Bs[32][64];
    int tid = threadIdx.x;
    int j0 = blockIdx.x * 64, b = blockIdx.y;
    const float* DrawT = ws_c + O_DRAWT;
    float acc[4][4] = {};
    int ty = tid >> 4, tx = tid & 15;
    for (int kc = 0; kc < 17; kc++) {
        int p0 = kc * 32;
        #pragma unroll
        for (int i = 0; i < 2; i++) {
            int lin = i * 256 + tid;
            int kp = lin >> 4, tg = lin & 15;
            float4 v = make_float4(0, 0, 0, 0);
            int p = p0 + kp;
            if (p < NP) v = *(const float4*)&DrawT[(size_t)p * 64 + tg * 4];
            *(float4*)&As[kp][tg * 4] = v;
        }
        #pragma unroll
        for (int i = 0; i < 2; i++) {
            int lin = i * 256 + tid;
            int kp = lin >> 4, jg = lin & 15;
            float4 v = make_float4(0, 0, 0, 0);
            int p = p0 + kp;
            if (p < NP) v = *(const float4*)&C[((size_t)b * NP + p) * JNT + j0 + jg * 4];
            *(float4*)&Bs[kp][jg * 4] = v;
        }
        __syncthreads();
        #pragma unroll
        for (int k = 0; k < 32; k++) {
            float4 a  = *(float4*)&As[k][ty * 4];
            float4 bv = *(float4*)&Bs[k][tx * 4];
            float av[4] = {a.x, a.y, a.z, a.w};
            float bw[4] = {bv.x, bv.y, bv.z, bv.w};
            #pragma unroll
            for (int i2 = 0; i2 < 4; i2++)
                #pragma unroll
                for (int jj = 0; jj < 4; jj++)
                    acc[i2][jj] = fmaf(av[i2], bw[jj], acc[i2][jj]);
        }
        __syncthreads();
    }
    #pragma unroll
    for (int i2 = 0; i2 < 4; i2++) {
        int t = ty * 4 + i2;
        size_t base = ((size_t)b * T_LEN + t) * JNT + j0 + tx * 4;
        *(float4*)&Y[base] = make_float4(acc[i2][0], acc[i2][1], acc[i2][2], acc[i2][3]);
    }
}

extern "C" void kernel_launch(void* const* d_in, const int* in_sizes, int n_in,
                              void* d_out, int out_size, void* d_ws, size_t ws_size,
                              hipStream_t stream) {
    const float* y  = (const float*)d_in[0];
    const float* r  = (const float*)d_in[1];
    const float* th = (const float*)d_in[2];
    float* ws   = (float*)d_ws;
    float* out  = (float*)d_out;
    float* dtd  = out;                 // fp32 scratch in Y region
    float* ln   = out + LN_OFF;
    float* Cgo  = out + Y_ELEMS;       // C_pred output region
    unsigned short* Ahg = (unsigned short*)(ws + O_AH);
    unsigned short* Alg = (unsigned short*)(ws + O_AL);
    float* ldty = ws + O_DTY;

    hipMemsetAsync(out,      0, (size_t)(DTD_F + 68) * 4, stream);
    hipMemsetAsync(ws + O_D, 0, (size_t)(T_LEN * NPP) * 4, stream);

    build_D<<<NP, 64, 0, stream>>>(r, th, ws);
    dtd_kernel<<<(NP * NP + 255) / 256, 256, 0, stream>>>(ws, dtd);
    lnorm1<<<64, 256, 0, stream>>>(dtd, ln);
    lnorm2<<<1, 64, 0, stream>>>(ln);
    dty_kernel<<<dim3(9, 8, 32), 256, 0, stream>>>(y, ws, ln, ldty);
    dtd_split<<<(MPAD * DTD_STR + 255) / 256, 256, 0, stream>>>(dtd, Ahg, Alg);

    hipFuncSetAttribute((const void*)fista_persist,
                        hipFuncAttributeMaxDynamicSharedMemorySize, LDS_BYTES);
    fista_persist<<<dim3(16, 32), 448, LDS_BYTES, stream>>>(Ahg, Alg, ldty, ln, Cgo);

    ypred_kernel<<<dim3(8, 32), 256, 0, stream>>>(ws, Cgo, out);
}

// Round 6
// 868.859 us; speedup vs baseline: 5.4708x; 1.2488x over previous
//
#include <hip/hip_runtime.h>
#include <cmath>

#define NP    513
#define NPP   516
#define T_LEN 64
#define JNT   512
#define NITER 30

// d_out scratch (floats): [0..348160) DtD fp32 [640][544]; [348160..348226) lnorm.
// Both overwritten later by ypred (Y region = 1,048,576 floats).
#define DTD_STR  544
#define DTD_F    (640 * DTD_STR)
#define LN_OFF   DTD_F
#define Y_ELEMS  1048576

// ws layout (floats)
#define O_DRAWT 0                          // [513][64] f32
#define O_D     32832                      // [64][516] f32 (pad cols zeroed)
#define O_DTY   65856                      // LdtY [32][512][544] f32 (L-scaled, j-major)
#define O_AH    8978752                    // Ahg k-major [68][576][8] bf16
#define O_AL    9135424                    // Alg k-major [68][576][8] bf16
#define O_LP    9292096                    // ldtyP packed [256][12][768][4] f32

#define MPAD  576       // padded M rows (12 waves x 48)
#define PSTR  544       // LdtY p-stride
#define LDSTR 552       // LDS B row stride (bf16 elems)
#define LDSJ  64
#define LDS_BYTES (LDSJ * LDSTR * 2 * 2)   // Bh + Bl = 141312

typedef short short8 __attribute__((ext_vector_type(8)));
typedef float f32x4  __attribute__((ext_vector_type(4)));

__device__ __forceinline__ unsigned short f2bf(float f) {
    unsigned u = __float_as_uint(f);
    return (unsigned short)((u + 0x7fffu + ((u >> 16) & 1u)) >> 16);
}
__device__ __forceinline__ float bf2f(unsigned short h) {
    return __uint_as_float((unsigned)h << 16);
}
__device__ __forceinline__ void split2(float f, unsigned short& h, unsigned short& l) {
    unsigned short hs = f2bf(f);
    h = hs;
    l = f2bf(f - bf2f(hs));
}

__global__ void build_D(const float* __restrict__ r, const float* __restrict__ th,
                        float* __restrict__ ws) {
    int p = blockIdx.x;          // 0..512
    int t = threadIdx.x;         // 0..63
    float val;
    if (p == 0) {
        val = 1.0f;
    } else if (p <= 256) {
        int n = p - 1;
        val = powf(r[n], (float)t) * cosf((float)t * th[n]);
    } else {
        int n = p - 257;
        val = powf(r[n], (float)t) * sinf((float)t * th[n]);
    }
    float s = val * val;
    #pragma unroll
    for (int off = 32; off; off >>= 1) s += __shfl_xor(s, off);
    float norm = sqrtf(s);
    ws[O_DRAWT + p * 64 + t] = val;
    ws[O_D + t * NPP + p]    = val / norm;
}

__global__ void dtd_kernel(const float* __restrict__ ws, float* __restrict__ dtd_out) {
    int idx = blockIdx.x * 256 + threadIdx.x;
    if (idx >= NP * NP) return;
    int p = idx / NP, q = idx % NP;
    const float* D = ws + O_D;
    float s = 0.0f;
    #pragma unroll 8
    for (int t = 0; t < T_LEN; t++) s = fmaf(D[t * NPP + p], D[t * NPP + q], s);
    dtd_out[(size_t)p * DTD_STR + q] = s;
}

__global__ __launch_bounds__(256) void lnorm1(const float* __restrict__ dtd_s,
                                              float* __restrict__ ln) {
    __shared__ float sm[256];
    int tid = threadIdx.x;
    size_t base = (size_t)blockIdx.x * 5440;
    float acc = 0.0f;
    for (int i = tid; i < 1360; i += 256) {
        float4 v = *(const float4*)&dtd_s[base + (size_t)i * 4];
        acc += v.x * v.x + v.y * v.y + v.z * v.z + v.w * v.w;
    }
    sm[tid] = acc; __syncthreads();
    for (int off = 128; off; off >>= 1) {
        if (tid < off) sm[tid] += sm[tid + off];
        __syncthreads();
    }
    if (tid == 0) ln[blockIdx.x] = sm[0];
}

__global__ void lnorm2(float* __restrict__ ln) {
    int lane = threadIdx.x;      // 64
    float v = ln[lane];
    #pragma unroll
    for (int off = 32; off; off >>= 1) v += __shfl_xor(v, off);
    if (lane == 0) {
        float L = 1.0f / sqrtf(v);
        ln[64] = L;
        ln[65] = L * 0.1f;
    }
}

// split DtD fp32 -> hi/lo bf16, k-major layout [68][576][8]
__global__ void dtd_split(const float* __restrict__ dtd_s,
                          unsigned short* __restrict__ Ahg,
                          unsigned short* __restrict__ Alg) {
    int idx = blockIdx.x * 256 + threadIdx.x;
    if (idx >= MPAD * DTD_STR) return;
    int m = idx / DTD_STR, k = idx % DTD_STR;
    float v = dtd_s[(size_t)m * DTD_STR + k];     // rows >=513 are zero
    unsigned short h, l;
    split2(v, h, l);
    size_t o = ((size_t)(k >> 3) * MPAD + m) * 8 + (k & 7);
    Ahg[o] = h;
    Alg[o] = l;
}

// LdtY[b][j][p] = L * sum_t D[t,p]*y[b,t,j], p-stride 544 (rows >=513 are zero)
__global__ __launch_bounds__(256) void dty_kernel(const float* __restrict__ y,
                                                  const float* __restrict__ ws,
                                                  const float* __restrict__ lnv,
                                                  float* __restrict__ ldty) {
    __shared__ float As[T_LEN][64];
    __shared__ float Bs[T_LEN][64];
    int tid = threadIdx.x;
    int p0 = blockIdx.x * 64, j0 = blockIdx.y * 64, b = blockIdx.z;
    const float* D = ws + O_D;
    #pragma unroll
    for (int i = 0; i < 4; i++) {
        int lin = i * 256 + tid;
        int kt = lin >> 4, pg = lin & 15;
        float4 v = make_float4(0, 0, 0, 0);
        int pp = p0 + pg * 4;
        if (pp < NPP) v = *(const float4*)&D[kt * NPP + pp];
        *(float4*)&As[kt][pg * 4] = v;
    }
    #pragma unroll
    for (int i = 0; i < 4; i++) {
        int lin = i * 256 + tid;
        int kt = lin >> 4, jg = lin & 15;
        *(float4*)&Bs[kt][jg * 4] =
            *(const float4*)&y[((size_t)b * T_LEN + kt) * JNT + j0 + jg * 4];
    }
    __syncthreads();
    int ty = tid >> 4, tx = tid & 15;
    float acc[4][4] = {};
    #pragma unroll 8
    for (int k = 0; k < T_LEN; k++) {
        float4 a  = *(float4*)&As[k][ty * 4];
        float4 bv = *(float4*)&Bs[k][tx * 4];
        float av[4] = {a.x, a.y, a.z, a.w};
        float bw[4] = {bv.x, bv.y, bv.z, bv.w};
        #pragma unroll
        for (int i2 = 0; i2 < 4; i2++)
            #pragma unroll
            for (int jj = 0; jj < 4; jj++)
                acc[i2][jj] = fmaf(av[i2], bw[jj], acc[i2][jj]);
    }
    float L = lnv[64];
    int p = p0 + ty * 4;
    if (p < PSTR) {
        #pragma unroll
        for (int jj = 0; jj < 4; jj++) {
            int j = j0 + tx * 4 + jj;
            float4 o = make_float4(acc[0][jj] * L, acc[1][jj] * L,
                                   acc[2][jj] * L, acc[3][jj] * L);
            *(float4*)&ldty[((size_t)b * JNT + j) * PSTR + p] = o;
        }
    }
}

// repack L*DtY into the fista block/thread/frag-coalesced layout:
// ldtyP[bid][f][tid][4], f = mi*4+ni, matching fista_persist's mapping.
__global__ __launch_bounds__(768) void pack_ldty(const float* __restrict__ ldty,
                                                 float* __restrict__ ldtyP) {
    int tid = threadIdx.x;
    int jb = blockIdx.x, b = blockIdx.y;
    int lane = tid & 63, w = tid >> 6;
    int l15 = lane & 15, l4 = lane >> 4;
    int bid = b * 8 + jb;
    float* lp = ldtyP + (size_t)bid * 12 * 768 * 4;
    #pragma unroll
    for (int f = 0; f < 12; ++f) {
        int mi = f >> 2, ni = f & 3;
        int p = w * 48 + mi * 16 + l4 * 4;
        int j = jb * 64 + ni * 16 + l15;
        float4 v = make_float4(0, 0, 0, 0);
        if (p < PSTR)
            v = *(const float4*)&ldty[((size_t)b * JNT + j) * PSTR + p];
        *(float4*)&lp[((size_t)f * 768 + tid) * 4] = v;
    }
}

// Persistent FISTA: all 30 iterations. Grid 8x32 = 256 blocks = 1 per CU.
// 768 threads = 12 waves; wave w owns rows [w*48, w*48+48) x all 64 j.
// State C_prev split bf16 hi/lo in LDS (141 KB); C_curr in registers;
// L*DtY streamed per iter from the packed coalesced layout.
__global__ __launch_bounds__(768, 3) void fista_persist(
    const unsigned short* __restrict__ Ahg,
    const unsigned short* __restrict__ Alg,
    const float* __restrict__ ldtyP,
    const float* __restrict__ lnv,      // [64]=L, [65]=thr
    float* __restrict__ Cg)             // [32][513][512]
{
    extern __shared__ unsigned short smv[];
    unsigned short* BhL = smv;                    // [64][552]
    unsigned short* BlL = smv + LDSJ * LDSTR;
    int tid = threadIdx.x;
    int jb = blockIdx.x, b = blockIdx.y;
    int lane = tid & 63, w = tid >> 6;            // w 0..11
    int l15 = lane & 15, l4 = lane >> 4;
    int bid = b * 8 + jb;

    {   // zero LDS state
        unsigned* p32 = (unsigned*)smv;
        for (int i = tid; i < LDS_BYTES / 4; i += 768) p32[i] = 0u;
    }

    float L = lnv[64], thr = lnv[65];
    const float* lp = ldtyP + (size_t)bid * 12 * 768 * 4;

    f32x4 ccur[3][4];
    #pragma unroll
    for (int mi = 0; mi < 3; ++mi)
        #pragma unroll
        for (int ni = 0; ni < 4; ++ni) ccur[mi][ni] = (f32x4){0, 0, 0, 0};

    __syncthreads();

    float t_prev = 1.0f;

    for (int it = 0; it < NITER; ++it) {
        float t_next = (1.0f + sqrtf(1.0f + 4.0f * t_prev * t_prev)) * 0.5f;
        float tc = (t_prev - 1.0f) / t_next;
        t_prev = t_next;

        f32x4 acc[3][4];
        #pragma unroll
        for (int mi = 0; mi < 3; ++mi)
            #pragma unroll
            for (int ni = 0; ni < 4; ++ni) acc[mi][ni] = (f32x4){0, 0, 0, 0};

        if (it > 0) {   // it==0: C_prev == 0 -> matmul is zero
            #pragma unroll 1
            for (int kc = 0; kc < 17; ++kc) {
                int q0 = kc * 32;
                // A fragments: 6 loads issued before MFMAs (distinct rows per wave)
                short8 ah[3], al[3];
                size_t abase = ((size_t)(kc * 4 + l4) * MPAD + w * 48 + l15) * 8;
                #pragma unroll
                for (int mi = 0; mi < 3; ++mi)
                    ah[mi] = *(const short8*)&Ahg[abase + mi * 128];
                #pragma unroll
                for (int mi = 0; mi < 3; ++mi)
                    al[mi] = *(const short8*)&Alg[abase + mi * 128];
                #pragma unroll
                for (int ni = 0; ni < 4; ++ni) {
                    int off = (ni * 16 + l15) * LDSTR + q0 + l4 * 8;
                    short8 bh = *(const short8*)&BhL[off];
                    short8 bl = *(const short8*)&BlL[off];
                    #pragma unroll
                    for (int mi = 0; mi < 3; ++mi) {
                        acc[mi][ni] = __builtin_amdgcn_mfma_f32_16x16x32_bf16(ah[mi], bh, acc[mi][ni], 0, 0, 0);
                        acc[mi][ni] = __builtin_amdgcn_mfma_f32_16x16x32_bf16(al[mi], bh, acc[mi][ni], 0, 0, 0);
                        acc[mi][ni] = __builtin_amdgcn_mfma_f32_16x16x32_bf16(ah[mi], bl, acc[mi][ni], 0, 0, 0);
                    }
                }
            }
        }
        __syncthreads();   // all B reads done before state overwrite

        #pragma unroll
        for (int mi = 0; mi < 3; ++mi) {
            int p = w * 48 + mi * 16 + l4 * 4;
            if (p > 512) continue;      // p quad start; 512 is the partial quad
            #pragma unroll
            for (int ni = 0; ni < 4; ++ni) {
                int f = mi * 4 + ni;
                float4 dv = *(const float4*)&lp[((size_t)f * 768 + tid) * 4];
                float dvv[4] = {dv.x, dv.y, dv.z, dv.w};
                int jl = ni * 16 + l15;
                int lo = jl * LDSTR + p;
                ushort4 h4 = *(const ushort4*)&BhL[lo];
                ushort4 g4 = *(const ushort4*)&BlL[lo];
                unsigned short hh[4] = {h4.x, h4.y, h4.z, h4.w};
                unsigned short gg[4] = {g4.x, g4.y, g4.z, g4.w};
                unsigned short nh[4], nl[4];
                #pragma unroll
                for (int rr = 0; rr < 4; ++rr) {
                    float cp = bf2f(hh[rr]) + bf2f(gg[rr]);
                    float v  = cp - L * acc[mi][ni][rr] + dvv[rr];
                    float a  = fabsf(v) - thr;
                    float st = (a > 0.0f) ? copysignf(a, v) : 0.0f;
                    float po = st + tc * (st - ccur[mi][ni][rr]);
                    ccur[mi][ni][rr] = st;
                    split2(po, nh[rr], nl[rr]);
                }
                *(ushort4*)&BhL[lo] = make_ushort4(nh[0], nh[1], nh[2], nh[3]);
                *(ushort4*)&BlL[lo] = make_ushort4(nl[0], nl[1], nl[2], nl[3]);
            }
        }
        __syncthreads();   // state visible before next matmul
    }

    // final store: C_pred = C_curr -> [b][p][j]
    #pragma unroll
    for (int mi = 0; mi < 3; ++mi) {
        int pq = w * 48 + mi * 16 + l4 * 4;
        if (pq > 512) continue;
        #pragma unroll
        for (int ni = 0; ni < 4; ++ni) {
            int j = jb * 64 + ni * 16 + l15;
            #pragma unroll
            for (int rr = 0; rr < 4; ++rr) {
                int p = pq + rr;
                if (p < NP) Cg[((size_t)b * NP + p) * JNT + j] = ccur[mi][ni][rr];
            }
        }
    }
}

// Y[b,t,j] = sum_p D_raw[t,p] * C[b,p,j]
__global__ __launch_bounds__(256) void ypred_kernel(const float* __restrict__ ws_c,
                                                    const float* __restrict__ C,
                                                    float* __restrict__ Y) {
    __shared__ float As[32][64];
    __shared__ float Bs[32][64];
    int tid = threadIdx.x;
    int j0 = blockIdx.x * 64, b = blockIdx.y;
    const float* DrawT = ws_c + O_DRAWT;
    float acc[4][4] = {};
    int ty = tid >> 4, tx = tid & 15;
    for (int kc = 0; kc < 17; kc++) {
        int p0 = kc * 32;
        #pragma unroll
        for (int i = 0; i < 2; i++) {
            int lin = i * 256 + tid;
            int kp = lin >> 4, tg = lin & 15;
            float4 v = make_float4(0, 0, 0, 0);
            int p = p0 + kp;
            if (p < NP) v = *(const float4*)&DrawT[(size_t)p * 64 + tg * 4];
            *(float4*)&As[kp][tg * 4] = v;
        }
        #pragma unroll
        for (int i = 0; i < 2; i++) {
            int lin = i * 256 + tid;
            int kp = lin >> 4, jg = lin & 15;
            float4 v = make_float4(0, 0, 0, 0);
            int p = p0 + kp;
            if (p < NP) v = *(const float4*)&C[((size_t)b * NP + p) * JNT + j0 + jg * 4];
            *(float4*)&Bs[kp][jg * 4] = v;
        }
        __syncthreads();
        #pragma unroll
        for (int k = 0; k < 32; k++) {
            float4 a  = *(float4*)&As[k][ty * 4];
            float4 bv = *(float4*)&Bs[k][tx * 4];
            float av[4] = {a.x, a.y, a.z, a.w};
            float bw[4] = {bv.x, bv.y, bv.z, bv.w};
            #pragma unroll
            for (int i2 = 0; i2 < 4; i2++)
                #pragma unroll
                for (int jj = 0; jj < 4; jj++)
                    acc[i2][jj] = fmaf(av[i2], bw[jj], acc[i2][jj]);
        }
        __syncthreads();
    }
    #pragma unroll
    for (int i2 = 0; i2 < 4; i2++) {
        int t = ty * 4 + i2;
        size_t base = ((size_t)b * T_LEN + t) * JNT + j0 + tx * 4;
        *(float4*)&Y[base] = make_float4(acc[i2][0], acc[i2][1], acc[i2][2], acc[i2][3]);
    }
}

extern "C" void kernel_launch(void* const* d_in, const int* in_sizes, int n_in,
                              void* d_out, int out_size, void* d_ws, size_t ws_size,
                              hipStream_t stream) {
    const float* y  = (const float*)d_in[0];
    const float* r  = (const float*)d_in[1];
    const float* th = (const float*)d_in[2];
    float* ws   = (float*)d_ws;
    float* out  = (float*)d_out;
    float* dtd  = out;                 // fp32 scratch in Y region
    float* ln   = out + LN_OFF;
    float* Cgo  = out + Y_ELEMS;       // C_pred output region
    unsigned short* Ahg = (unsigned short*)(ws + O_AH);
    unsigned short* Alg = (unsigned short*)(ws + O_AL);
    float* ldty  = ws + O_DTY;
    float* ldtyP = ws + O_LP;

    hipMemsetAsync(out,      0, (size_t)(DTD_F + 68) * 4, stream);
    hipMemsetAsync(ws + O_D, 0, (size_t)(T_LEN * NPP) * 4, stream);

    build_D<<<NP, 64, 0, stream>>>(r, th, ws);
    dtd_kernel<<<(NP * NP + 255) / 256, 256, 0, stream>>>(ws, dtd);
    lnorm1<<<64, 256, 0, stream>>>(dtd, ln);
    lnorm2<<<1, 64, 0, stream>>>(ln);
    dty_kernel<<<dim3(9, 8, 32), 256, 0, stream>>>(y, ws, ln, ldty);
    dtd_split<<<(MPAD * DTD_STR + 255) / 256, 256, 0, stream>>>(dtd, Ahg, Alg);
    pack_ldty<<<dim3(8, 32), 768, 0, stream>>>(ldty, ldtyP);

    hipFuncSetAttribute((const void*)fista_persist,
                        hipFuncAttributeMaxDynamicSharedMemorySize, LDS_BYTES);
    fista_persist<<<dim3(8, 32), 768, LDS_BYTES, stream>>>(Ahg, Alg, ldtyP, ln, Cgo);

    ypred_kernel<<<dim3(8, 32), 256, 0, stream>>>(ws, Cgo, out);
}

// Round 7
// 703.973 us; speedup vs baseline: 6.7521x; 1.2342x over previous
//
#include <hip/hip_runtime.h>
#include <cmath>

#define NP    513
#define NPP   516
#define T_LEN 64
#define JNT   512
#define NITER 30

// d_out scratch (floats): [0..348160) DtD fp32 [640][544]; [348160..348226) lnorm.
// Both overwritten later by ypred (Y region = 1,048,576 floats).
#define DTD_STR  544
#define DTD_F    (640 * DTD_STR)
#define LN_OFF   DTD_F
#define Y_ELEMS  1048576

// ws layout (floats)
#define O_DRAWT 0                          // [513][64] f32
#define O_D     32832                      // [64][516] f32 (pad cols zeroed)
#define O_DTY   65856                      // LdtY [32][512][544] f32 (L-scaled, j-major)
#define O_DG1H  8978752                    // Dg1 hi  k-major [68][64][8] bf16
#define O_DG1L  8996160                    // Dg1 lo
#define O_DTGH  9013568                    // Dtg hi  k-major [8][576][8] bf16
#define O_DTGL  9032000                    // Dtg lo
#define O_LP    9050432                    // ldtyP packed [256][12][768][4] f32

#define MPAD  576
#define PSTR  544       // LdtY p-stride
#define LDSTR 552       // LDS state row stride (bf16 elems)
#define USTR  76        // Utf row stride (f32)
#define LDS_BYTES (2 * 64 * LDSTR * 2 + 64 * USTR * 4)   // 141312 + 19456 = 160768

typedef short short8 __attribute__((ext_vector_type(8)));
typedef float f32x4  __attribute__((ext_vector_type(4)));

__device__ __forceinline__ unsigned short f2bf(float f) {
    unsigned u = __float_as_uint(f);
    return (unsigned short)((u + 0x7fffu + ((u >> 16) & 1u)) >> 16);
}
__device__ __forceinline__ float bf2f(unsigned short h) {
    return __uint_as_float((unsigned)h << 16);
}
__device__ __forceinline__ void split2(float f, unsigned short& h, unsigned short& l) {
    unsigned short hs = f2bf(f);
    h = hs;
    l = f2bf(f - bf2f(hs));
}

__global__ void build_D(const float* __restrict__ r, const float* __restrict__ th,
                        float* __restrict__ ws) {
    int p = blockIdx.x;          // 0..512
    int t = threadIdx.x;         // 0..63
    float val;
    if (p == 0) {
        val = 1.0f;
    } else if (p <= 256) {
        int n = p - 1;
        val = powf(r[n], (float)t) * cosf((float)t * th[n]);
    } else {
        int n = p - 257;
        val = powf(r[n], (float)t) * sinf((float)t * th[n]);
    }
    float s = val * val;
    #pragma unroll
    for (int off = 32; off; off >>= 1) s += __shfl_xor(s, off);
    float norm = sqrtf(s);
    ws[O_DRAWT + p * 64 + t] = val;
    ws[O_D + t * NPP + p]    = val / norm;
}

__global__ void dtd_kernel(const float* __restrict__ ws, float* __restrict__ dtd_out) {
    int idx = blockIdx.x * 256 + threadIdx.x;
    if (idx >= NP * NP) return;
    int p = idx / NP, q = idx % NP;
    const float* D = ws + O_D;
    float s = 0.0f;
    #pragma unroll 8
    for (int t = 0; t < T_LEN; t++) s = fmaf(D[t * NPP + p], D[t * NPP + q], s);
    dtd_out[(size_t)p * DTD_STR + q] = s;
}

__global__ __launch_bounds__(256) void lnorm1(const float* __restrict__ dtd_s,
                                              float* __restrict__ ln) {
    __shared__ float sm[256];
    int tid = threadIdx.x;
    size_t base = (size_t)blockIdx.x * 5440;
    float acc = 0.0f;
    for (int i = tid; i < 1360; i += 256) {
        float4 v = *(const float4*)&dtd_s[base + (size_t)i * 4];
        acc += v.x * v.x + v.y * v.y + v.z * v.z + v.w * v.w;
    }
    sm[tid] = acc; __syncthreads();
    for (int off = 128; off; off >>= 1) {
        if (tid < off) sm[tid] += sm[tid + off];
        __syncthreads();
    }
    if (tid == 0) ln[blockIdx.x] = sm[0];
}

__global__ void lnorm2(float* __restrict__ ln) {
    int lane = threadIdx.x;      // 64
    float v = ln[lane];
    #pragma unroll
    for (int off = 32; off; off >>= 1) v += __shfl_xor(v, off);
    if (lane == 0) {
        float L = 1.0f / sqrtf(v);
        ln[64] = L;
        ln[65] = L * 0.1f;
    }
}

// D hi/lo, k-major [68 qchunk][64 t][8] (q >= 513 zero)
__global__ void build_dg1(const float* __restrict__ ws,
                          unsigned short* __restrict__ Dg1h,
                          unsigned short* __restrict__ Dg1l) {
    int idx = blockIdx.x * 256 + threadIdx.x;
    if (idx >= 68 * 64 * 8) return;
    int i = idx & 7, t = (idx >> 3) & 63, kc8 = idx >> 9;
    int q = kc8 * 8 + i;
    float v = (q < NPP) ? ws[O_D + t * NPP + q] : 0.0f;   // 513..515 are zeroed pads
    unsigned short h, l;
    split2(v, h, l);
    Dg1h[idx] = h;
    Dg1l[idx] = l;
}

// D^T hi/lo, k-major [8 tchunk][576 p][8] (p >= 513 zero)
__global__ void build_dtg(const float* __restrict__ ws,
                          unsigned short* __restrict__ Dtgh,
                          unsigned short* __restrict__ Dtgl) {
    int idx = blockIdx.x * 256 + threadIdx.x;
    if (idx >= 8 * 576 * 8) return;
    int i = idx & 7, p = (idx >> 3) % 576, tc = idx / 4608;
    int t = tc * 8 + i;
    float v = (p < NP) ? ws[O_D + t * NPP + p] : 0.0f;
    unsigned short h, l;
    split2(v, h, l);
    Dtgh[idx] = h;
    Dtgl[idx] = l;
}

// LdtY[b][j][p] = L * sum_t D[t,p]*y[b,t,j], p-stride 544
__global__ __launch_bounds__(256) void dty_kernel(const float* __restrict__ y,
                                                  const float* __restrict__ ws,
                                                  const float* __restrict__ lnv,
                                                  float* __restrict__ ldty) {
    __shared__ float As[T_LEN][64];
    __shared__ float Bs[T_LEN][64];
    int tid = threadIdx.x;
    int p0 = blockIdx.x * 64, j0 = blockIdx.y * 64, b = blockIdx.z;
    const float* D = ws + O_D;
    #pragma unroll
    for (int i = 0; i < 4; i++) {
        int lin = i * 256 + tid;
        int kt = lin >> 4, pg = lin & 15;
        float4 v = make_float4(0, 0, 0, 0);
        int pp = p0 + pg * 4;
        if (pp < NPP) v = *(const float4*)&D[kt * NPP + pp];
        *(float4*)&As[kt][pg * 4] = v;
    }
    #pragma unroll
    for (int i = 0; i < 4; i++) {
        int lin = i * 256 + tid;
        int kt = lin >> 4, jg = lin & 15;
        *(float4*)&Bs[kt][jg * 4] =
            *(const float4*)&y[((size_t)b * T_LEN + kt) * JNT + j0 + jg * 4];
    }
    __syncthreads();
    int ty = tid >> 4, tx = tid & 15;
    float acc[4][4] = {};
    #pragma unroll 8
    for (int k = 0; k < T_LEN; k++) {
        float4 a  = *(float4*)&As[k][ty * 4];
        float4 bv = *(float4*)&Bs[k][tx * 4];
        float av[4] = {a.x, a.y, a.z, a.w};
        float bw[4] = {bv.x, bv.y, bv.z, bv.w};
        #pragma unroll
        for (int i2 = 0; i2 < 4; i2++)
            #pragma unroll
            for (int jj = 0; jj < 4; jj++)
                acc[i2][jj] = fmaf(av[i2], bw[jj], acc[i2][jj]);
    }
    float L = lnv[64];
    int p = p0 + ty * 4;
    if (p < PSTR) {
        #pragma unroll
        for (int jj = 0; jj < 4; jj++) {
            int j = j0 + tx * 4 + jj;
            float4 o = make_float4(acc[0][jj] * L, acc[1][jj] * L,
                                   acc[2][jj] * L, acc[3][jj] * L);
            *(float4*)&ldty[((size_t)b * JNT + j) * PSTR + p] = o;
        }
    }
}

// repack L*DtY into [bid][f][tid][4] matching fista's lane mapping
__global__ __launch_bounds__(768) void pack_ldty(const float* __restrict__ ldty,
                                                 float* __restrict__ ldtyP) {
    int tid = threadIdx.x;
    int jb = blockIdx.x, b = blockIdx.y;
    int lane = tid & 63, w = tid >> 6;
    int l15 = lane & 15, l4 = lane >> 4;
    int bid = b * 8 + jb;
    float* lp = ldtyP + (size_t)bid * 12 * 768 * 4;
    #pragma unroll
    for (int f = 0; f < 12; ++f) {
        int mi = f >> 2, ni = f & 3;
        int p = w * 48 + mi * 16 + l4 * 4;
        int j = jb * 64 + ni * 16 + l15;
        float4 v = make_float4(0, 0, 0, 0);
        if (p < PSTR)
            v = *(const float4*)&ldty[((size_t)b * JNT + j) * PSTR + p];
        *(float4*)&lp[((size_t)f * 768 + tid) * 4] = v;
    }
}

// Persistent FISTA with rank-64 factorization: grad = D^T(D C) - DtY.
// 256 blocks (1/CU), 768 thr = 12 waves.
// GEMM1 (U^T[j][t] = C^T D^T, K=544): waves 0-3 (nt = w), output -> Utf f32 LDS.
// GEMM2 (V[p][j] = Dt U, K=64): all 12 waves, wave w owns p in [w*48, w*48+48).
// State C_prev split bf16 hi/lo in LDS; C_curr + L*DtY in registers (permanent).
__global__ __launch_bounds__(768, 3) void fista_persist(
    const unsigned short* __restrict__ Dg1h,
    const unsigned short* __restrict__ Dg1l,
    const unsigned short* __restrict__ Dtgh,
    const unsigned short* __restrict__ Dtgl,
    const float* __restrict__ ldtyP,
    const float* __restrict__ lnv,      // [64]=L, [65]=thr
    float* __restrict__ Cg)             // [32][513][512]
{
    extern __shared__ unsigned short smv[];
    unsigned short* BhL = smv;                    // [64][552]
    unsigned short* BlL = smv + 64 * LDSTR;
    float* Utf = (float*)(smv + 2 * 64 * LDSTR);  // [64][76]
    int tid = threadIdx.x;
    int jb = blockIdx.x, b = blockIdx.y;
    int lane = tid & 63, w = tid >> 6;            // w 0..11
    int l15 = lane & 15, l4 = lane >> 4;
    int bid = b * 8 + jb;

    {   // zero state (141312 B = 35328 dwords)
        unsigned* p32 = (unsigned*)smv;
        for (int i = tid; i < 64 * LDSTR; i += 768) p32[i] = 0u;
    }

    float L = lnv[64], thr = lnv[65];
    const float* lp = ldtyP + (size_t)bid * 12 * 768 * 4;

    // permanent: L*DtY fragments + C_curr
    f32x4 ldtyR[3][4];
    f32x4 ccur[3][4];
    #pragma unroll
    for (int mi = 0; mi < 3; ++mi)
        #pragma unroll
        for (int ni = 0; ni < 4; ++ni) {
            ccur[mi][ni] = (f32x4){0, 0, 0, 0};
            float4 v = *(const float4*)&lp[((size_t)(mi * 4 + ni) * 768 + tid) * 4];
            ldtyR[mi][ni] = (f32x4){v.x, v.y, v.z, v.w};
        }
    __syncthreads();

    float t_prev = 1.0f;

    #pragma unroll 1
    for (int it = 0; it < NITER; ++it) {
        float t_next = (1.0f + sqrtf(1.0f + 4.0f * t_prev * t_prev)) * 0.5f;
        float tc = (t_prev - 1.0f) / t_next;
        t_prev = t_next;

        if (it > 0 && w < 4) {
            // ---- GEMM1: U^T[j][t] = sum_q state[j][q] * D[t][q], nt = w ----
            int nt = w;
            f32x4 a1[4] = {(f32x4){0,0,0,0}, (f32x4){0,0,0,0},
                           (f32x4){0,0,0,0}, (f32x4){0,0,0,0}};
            size_t bo0 = ((size_t)l4 * 64 + nt * 16 + l15) * 8;
            short8 pbh = *(const short8*)&Dg1h[bo0];
            short8 pbl = *(const short8*)&Dg1l[bo0];
            #pragma unroll 1
            for (int kc = 0; kc < 17; ++kc) {
                short8 bh = pbh, bl = pbl;
                if (kc < 16) {
                    size_t bo = ((size_t)((kc + 1) * 4 + l4) * 64 + nt * 16 + l15) * 8;
                    pbh = *(const short8*)&Dg1h[bo];
                    pbl = *(const short8*)&Dg1l[bo];
                }
                int q0 = kc * 32;
                #pragma unroll
                for (int mj = 0; mj < 4; ++mj) {
                    int off = (mj * 16 + l15) * LDSTR + q0 + l4 * 8;
                    short8 sh = *(const short8*)&BhL[off];
                    short8 sl = *(const short8*)&BlL[off];
                    a1[mj] = __builtin_amdgcn_mfma_f32_16x16x32_bf16(sh, bh, a1[mj], 0, 0, 0);
                    a1[mj] = __builtin_amdgcn_mfma_f32_16x16x32_bf16(sl, bh, a1[mj], 0, 0, 0);
                    a1[mj] = __builtin_amdgcn_mfma_f32_16x16x32_bf16(sh, bl, a1[mj], 0, 0, 0);
                }
            }
            #pragma unroll
            for (int mj = 0; mj < 4; ++mj)
                #pragma unroll
                for (int rr = 0; rr < 4; ++rr)
                    Utf[(mj * 16 + l4 * 4 + rr) * USTR + nt * 16 + l15] = a1[mj][rr];
        }
        __syncthreads();

        // ---- Dt fragments (L2-resident 147KB buffer) ----
        short8 dth[3][2], dtl[3][2];
        if (it > 0) {
            #pragma unroll
            for (int mi = 0; mi < 3; ++mi)
                #pragma unroll
                for (int kc2 = 0; kc2 < 2; ++kc2) {
                    size_t o = ((size_t)(kc2 * 4 + l4) * MPAD + w * 48 + mi * 16 + l15) * 8;
                    dth[mi][kc2] = *(const short8*)&Dtgh[o];
                    dtl[mi][kc2] = *(const short8*)&Dtgl[o];
                }
        }

        // ---- GEMM2 + fused elementwise, per j-fragment ----
        #pragma unroll 1
        for (int nf = 0; nf < 4; ++nf) {
            f32x4 acc[3] = {(f32x4){0,0,0,0}, (f32x4){0,0,0,0}, (f32x4){0,0,0,0}};
            if (it > 0) {
                #pragma unroll
                for (int kc2 = 0; kc2 < 2; ++kc2) {
                    int uo = (nf * 16 + l15) * USTR + kc2 * 32 + l4 * 8;
                    float4 u0 = *(const float4*)&Utf[uo];
                    float4 u1 = *(const float4*)&Utf[uo + 4];
                    union { short8 v; unsigned short u[8]; } uh, ul;
                    float uv[8] = {u0.x, u0.y, u0.z, u0.w, u1.x, u1.y, u1.z, u1.w};
                    #pragma unroll
                    for (int e = 0; e < 8; ++e) split2(uv[e], uh.u[e], ul.u[e]);
                    #pragma unroll
                    for (int mi = 0; mi < 3; ++mi) {
                        acc[mi] = __builtin_amdgcn_mfma_f32_16x16x32_bf16(dth[mi][kc2], uh.v, acc[mi], 0, 0, 0);
                        acc[mi] = __builtin_amdgcn_mfma_f32_16x16x32_bf16(dtl[mi][kc2], uh.v, acc[mi], 0, 0, 0);
                        acc[mi] = __builtin_amdgcn_mfma_f32_16x16x32_bf16(dth[mi][kc2], ul.v, acc[mi], 0, 0, 0);
                    }
                }
            }
            #pragma unroll
            for (int mi = 0; mi < 3; ++mi) {
                int p = w * 48 + mi * 16 + l4 * 4;
                if (p > 512) continue;
                int jl = nf * 16 + l15;
                int lo = jl * LDSTR + p;
                ushort4 h4 = *(const ushort4*)&BhL[lo];
                ushort4 g4 = *(const ushort4*)&BlL[lo];
                unsigned short hh[4] = {h4.x, h4.y, h4.z, h4.w};
                unsigned short gg[4] = {g4.x, g4.y, g4.z, g4.w};
                unsigned short nh[4], nl[4];
                #pragma unroll
                for (int rr = 0; rr < 4; ++rr) {
                    float cp = bf2f(hh[rr]) + bf2f(gg[rr]);
                    float v  = cp - L * acc[mi][rr] + ldtyR[mi][nf][rr];
                    float a  = fabsf(v) - thr;
                    float st = (a > 0.0f) ? copysignf(a, v) : 0.0f;
                    float po = st + tc * (st - ccur[mi][nf][rr]);
                    ccur[mi][nf][rr] = st;
                    split2(po, nh[rr], nl[rr]);
                }
                *(ushort4*)&BhL[lo] = make_ushort4(nh[0], nh[1], nh[2], nh[3]);
                *(ushort4*)&BlL[lo] = make_ushort4(nl[0], nl[1], nl[2], nl[3]);
            }
        }
        __syncthreads();
    }

    // final store: C_pred = C_curr -> [b][p][j]
    #pragma unroll
    for (int mi = 0; mi < 3; ++mi) {
        int pq = w * 48 + mi * 16 + l4 * 4;
        if (pq > 512) continue;
        #pragma unroll
        for (int ni = 0; ni < 4; ++ni) {
            int j = jb * 64 + ni * 16 + l15;
            #pragma unroll
            for (int rr = 0; rr < 4; ++rr) {
                int p = pq + rr;
                if (p < NP) Cg[((size_t)b * NP + p) * JNT + j] = ccur[mi][ni][rr];
            }
        }
    }
}

// Y[b,t,j] = sum_p D_raw[t,p] * C[b,p,j]
__global__ __launch_bounds__(256) void ypred_kernel(const float* __restrict__ ws_c,
                                                    const float* __restrict__ C,
                                                    float* __restrict__ Y) {
    __shared__ float As[32][64];
    __shared__ float Bs[32][64];
    int tid = threadIdx.x;
    int j0 = blockIdx.x * 64, b = blockIdx.y;
    const float* DrawT = ws_c + O_DRAWT;
    float acc[4][4] = {};
    int ty = tid >> 4, tx = tid & 15;
    for (int kc = 0; kc < 17; kc++) {
        int p0 = kc * 32;
        #pragma unroll
        for (int i = 0; i < 2; i++) {
            int lin = i * 256 + tid;
            int kp = lin >> 4, tg = lin & 15;
            float4 v = make_float4(0, 0, 0, 0);
            int p = p0 + kp;
            if (p < NP) v = *(const float4*)&DrawT[(size_t)p * 64 + tg * 4];
            *(float4*)&As[kp][tg * 4] = v;
        }
        #pragma unroll
        for (int i = 0; i < 2; i++) {
            int lin = i * 256 + tid;
            int kp = lin >> 4, jg = lin & 15;
            float4 v = make_float4(0, 0, 0, 0);
            int p = p0 + kp;
            if (p < NP) v = *(const float4*)&C[((size_t)b * NP + p) * JNT + j0 + jg * 4];
            *(float4*)&Bs[kp][jg * 4] = v;
        }
        __syncthreads();
        #pragma unroll
        for (int k = 0; k < 32; k++) {
            float4 a  = *(float4*)&As[k][ty * 4];
            float4 bv = *(float4*)&Bs[k][tx * 4];
            float av[4] = {a.x, a.y, a.z, a.w};
            float bw[4] = {bv.x, bv.y, bv.z, bv.w};
            #pragma unroll
            for (int i2 = 0; i2 < 4; i2++)
                #pragma unroll
                for (int jj = 0; jj < 4; jj++)
                    acc[i2][jj] = fmaf(av[i2], bw[jj], acc[i2][jj]);
        }
        __syncthreads();
    }
    #pragma unroll
    for (int i2 = 0; i2 < 4; i2++) {
        int t = ty * 4 + i2;
        size_t base = ((size_t)b * T_LEN + t) * JNT + j0 + tx * 4;
        *(float4*)&Y[base] = make_float4(acc[i2][0], acc[i2][1], acc[i2][2], acc[i2][3]);
    }
}

extern "C" void kernel_launch(void* const* d_in, const int* in_sizes, int n_in,
                              void* d_out, int out_size, void* d_ws, size_t ws_size,
                              hipStream_t stream) {
    const float* y  = (const float*)d_in[0];
    const float* r  = (const float*)d_in[1];
    const float* th = (const float*)d_in[2];
    float* ws   = (float*)d_ws;
    float* out  = (float*)d_out;
    float* dtd  = out;                 // fp32 scratch in Y region
    float* ln   = out + LN_OFF;
    float* Cgo  = out + Y_ELEMS;       // C_pred output region
    unsigned short* Dg1h = (unsigned short*)(ws + O_DG1H);
    unsigned short* Dg1l = (unsigned short*)(ws + O_DG1L);
    unsigned short* Dtgh = (unsigned short*)(ws + O_DTGH);
    unsigned short* Dtgl = (unsigned short*)(ws + O_DTGL);
    float* ldty  = ws + O_DTY;
    float* ldtyP = ws + O_LP;

    hipMemsetAsync(out,      0, (size_t)(DTD_F + 68) * 4, stream);
    hipMemsetAsync(ws + O_D, 0, (size_t)(T_LEN * NPP) * 4, stream);

    build_D<<<NP, 64, 0, stream>>>(r, th, ws);
    dtd_kernel<<<(NP * NP + 255) / 256, 256, 0, stream>>>(ws, dtd);
    lnorm1<<<64, 256, 0, stream>>>(dtd, ln);
    lnorm2<<<1, 64, 0, stream>>>(ln);
    dty_kernel<<<dim3(9, 8, 32), 256, 0, stream>>>(y, ws, ln, ldty);
    build_dg1<<<(68 * 64 * 8 + 255) / 256, 256, 0, stream>>>(ws, Dg1h, Dg1l);
    build_dtg<<<(8 * 576 * 8 + 255) / 256, 256, 0, stream>>>(ws, Dtgh, Dtgl);
    pack_ldty<<<dim3(8, 32), 768, 0, stream>>>(ldty, ldtyP);

    hipFuncSetAttribute((const void*)fista_persist,
                        hipFuncAttributeMaxDynamicSharedMemorySize, LDS_BYTES);
    fista_persist<<<dim3(8, 32), 768, LDS_BYTES, stream>>>(Dg1h, Dg1l, Dtgh, Dtgl,
                                                           ldtyP, ln, Cgo);

    ypred_kernel<<<dim3(8, 32), 256, 0, stream>>>(ws, Cgo, out);
}